// Round 1
// baseline (43009.570 us; speedup 1.0000x reference)
//
#include <hip/hip_runtime.h>
#include <hip/hip_cooperative_groups.h>

namespace cg = cooperative_groups;

#define HDIM 1024
#define BDIM 64
#define TDIM 512
#define BH   (BDIM * HDIM)   // 65536
#define WPAD 1032            // weight LDS row stride (+8 shorts -> conflict-free-ish)

typedef __bf16 bf16x8 __attribute__((ext_vector_type(8)));
typedef float  f32x4  __attribute__((ext_vector_type(4)));

__device__ __forceinline__ float sigf(float x) { return 1.0f / (1.0f + expf(-x)); }

__device__ __forceinline__ bf16x8 cvt8(const float* p) {
    const f32x4* q = (const f32x4*)p;
    f32x4 a = q[0], b = q[1];
    bf16x8 r;
    r[0] = (__bf16)a[0]; r[1] = (__bf16)a[1]; r[2] = (__bf16)a[2]; r[3] = (__bf16)a[3];
    r[4] = (__bf16)b[0]; r[5] = (__bf16)b[1]; r[6] = (__bf16)b[2]; r[7] = (__bf16)b[3];
    return r;
}

// Dual GEMM: acc1 += A1 * B1, acc2 += A2 * B2 over K=1024, one wave computes a
// 16(batch) x 16(gate-row) tile. Pointers are pre-offset by lane (row + quad*8).
template <bool A1_F32>
__device__ __forceinline__ void dual_gemm(const void* a1p, const __bf16* a2p,
                                          const __bf16* b1p, const __bf16* b2p,
                                          f32x4& acc1, f32x4& acc2) {
#pragma unroll 4
    for (int ks = 0; ks < HDIM; ks += 32) {
        bf16x8 va;
        if constexpr (A1_F32)
            va = cvt8((const float*)a1p + ks);
        else
            va = *(const bf16x8*)((const __bf16*)a1p + ks);
        bf16x8 vb = *(const bf16x8*)(a2p + ks);
        bf16x8 wa = *(const bf16x8*)(b1p + ks);
        bf16x8 wb = *(const bf16x8*)(b2p + ks);
        acc1 = __builtin_amdgcn_mfma_f32_16x16x32_bf16(va, wa, acc1, 0, 0, 0);
        acc2 = __builtin_amdgcn_mfma_f32_16x16x32_bf16(vb, wb, acc2, 0, 0, 0);
    }
}

// gates -> LSTM cell -> BN -> dropout-mask. Returns masked BN output, h via ref.
__device__ __forceinline__ float cell_bn(const f32x4& acc1, const f32x4& acc2,
                                         const float* bias_s, float* gbuf, float* xh,
                                         float* stat_m, float* stat_r,
                                         float& c, float gam, float bet, float msk,
                                         float& hout,
                                         int lane, int wav, int quad, int qm,
                                         int bb, int jj) {
#pragma unroll
    for (int r = 0; r < 4; r++)
        gbuf[(wav * 16 + quad * 4 + r) * 17 + qm] = acc1[r] + acc2[r] + bias_s[qm];
    __syncthreads();
    // thread (bb, jj): gather its 4 gates (n = gate*4 + jj)
    float gi = gbuf[bb * 17 + 0 + jj];
    float gf = gbuf[bb * 17 + 4 + jj];
    float gg = gbuf[bb * 17 + 8 + jj];
    float go = gbuf[bb * 17 + 12 + jj];
    c = sigf(gf) * c + sigf(gi) * tanhf(gg);
    float h = sigf(go) * tanhf(c);
    hout = h;
    xh[jj * 64 + bb] = h;
    __syncthreads();
    // BN stats: wave w reduces feature w over the 64 batch rows
    {
        float v = xh[wav * 64 + lane];
        float s1 = v, s2 = v * v;
#pragma unroll
        for (int off = 32; off; off >>= 1) {
            s1 += __shfl_xor(s1, off);
            s2 += __shfl_xor(s2, off);
        }
        if (lane == 0) {
            float m  = s1 * (1.0f / 64.0f);
            float va = s2 * (1.0f / 64.0f) - m * m;
            stat_m[wav] = m;
            stat_r[wav] = rsqrtf(va + 1e-5f);
        }
    }
    __syncthreads();
    return ((h - stat_m[jj]) * stat_r[jj] * gam + bet) * msk;
}

__global__ void __launch_bounds__(256, 1) rnn_all(
    const int* __restrict__ x, const float* __restrict__ tv,
    const float* __restrict__ emb,
    const float* __restrict__ w_ih1, const float* __restrict__ w_hh1,
    const float* __restrict__ b_ih1, const float* __restrict__ b_hh1,
    const float* __restrict__ gamma1, const float* __restrict__ beta1,
    const float* __restrict__ w_ih2, const float* __restrict__ w_hh2,
    const float* __restrict__ b_ih2, const float* __restrict__ b_hh2,
    const float* __restrict__ gamma2, const float* __restrict__ beta2,
    const float* __restrict__ fc_w, const float* __restrict__ fc_b,
    const float* __restrict__ mask1, const float* __restrict__ mask2,
    __bf16* __restrict__ h1buf, __bf16* __restrict__ h2buf,
    __bf16* __restrict__ o1buf, float* __restrict__ pooled,
    float* __restrict__ out) {
    __shared__ __bf16 wih1_s[16 * WPAD];
    __shared__ __bf16 whh1_s[16 * WPAD];
    __shared__ __bf16 wih2_s[16 * WPAD];
    __shared__ __bf16 whh2_s[16 * WPAD];
    __shared__ float bias1_s[16], bias2_s[16];
    __shared__ float gbuf[64 * 17];
    __shared__ float xh[4 * 64];
    __shared__ float stat_m[4], stat_r[4];

    cg::grid_group grid = cg::this_grid();

    const int tid   = threadIdx.x;
    const int blk   = blockIdx.x;
    const int fbase = blk * 4;

    // ---- load this block's 16 gate rows of each weight matrix into LDS (bf16)
    for (int idx = tid; idx < 16 * HDIM; idx += 256) {
        int n = idx >> 10, k = idx & 1023;
        int row = (n >> 2) * HDIM + fbase + (n & 3);   // gate*H + feature
        wih1_s[n * WPAD + k] = (__bf16)w_ih1[row * HDIM + k];
        whh1_s[n * WPAD + k] = (__bf16)w_hh1[row * HDIM + k];
        wih2_s[n * WPAD + k] = (__bf16)w_ih2[row * HDIM + k];
        whh2_s[n * WPAD + k] = (__bf16)w_hh2[row * HDIM + k];
    }
    if (tid < 16) {
        int row = (tid >> 2) * HDIM + fbase + (tid & 3);
        bias1_s[tid] = b_ih1[row] + b_hh1[row];
        bias2_s[tid] = b_ih2[row] + b_hh2[row];
    }
    __syncthreads();

    // ---- per-thread roles
    const int lane = tid & 63;
    const int wav  = tid >> 6;
    const int qm   = lane & 15;        // A-row-within-tile / B-col (gate row n)
    const int quad = lane >> 4;
    const int arow = wav * 16 + qm;    // batch row this lane loads A for
    const int k0q  = quad * 8;         // k offset within 32-wide K step

    const int bb   = tid >> 2;         // batch row this thread owns for cell/BN
    const int jj   = tid & 3;          // feature-within-block
    const int feat = fbase + jj;

    const float g1v = gamma1[feat], be1v = beta1[feat], m1v = mask1[bb * HDIM + feat];
    const float g2v = gamma2[feat], be2v = beta2[feat], m2v = mask2[bb * HDIM + feat];
    float c1 = 0.0f, c2 = 0.0f, pmax = -1e30f;

    const __bf16* bw_ih1 = wih1_s + qm * WPAD + k0q;
    const __bf16* bw_hh1 = whh1_s + qm * WPAD + k0q;
    const __bf16* bw_ih2 = wih2_s + qm * WPAD + k0q;
    const __bf16* bw_hh2 = whh2_s + qm * WPAD + k0q;

    grid.sync();   // weights loaded everywhere; ws buffers (memset) visible

#pragma unroll 1
    for (int t = 0; t < TDIM; t++) {
        const int p = t & 1;
        // ================= phase 1: layer-1 LSTM + BN1 =================
        {
            const float*  a1 = emb + (size_t)x[arow * TDIM + t] * HDIM + k0q;
            const __bf16* a2 = h1buf + p * BH + arow * HDIM + k0q;
            f32x4 acc1 = {0.f, 0.f, 0.f, 0.f}, acc2 = {0.f, 0.f, 0.f, 0.f};
            dual_gemm<true>(a1, a2, bw_ih1, bw_hh1, acc1, acc2);
            float h1f;
            float o1 = cell_bn(acc1, acc2, bias1_s, gbuf, xh, stat_m, stat_r,
                               c1, g1v, be1v, m1v, h1f, lane, wav, quad, qm, bb, jj);
            h1buf[(1 - p) * BH + bb * HDIM + feat] = (__bf16)h1f;
            o1buf[bb * HDIM + feat] = (__bf16)o1;
        }
        grid.sync();
        // ================= phase 2: layer-2 LSTM + BN2 + maxpool =======
        {
            const __bf16* a1 = o1buf + arow * HDIM + k0q;
            const __bf16* a2 = h2buf + p * BH + arow * HDIM + k0q;
            f32x4 acc1 = {0.f, 0.f, 0.f, 0.f}, acc2 = {0.f, 0.f, 0.f, 0.f};
            dual_gemm<false>(a1, a2, bw_ih2, bw_hh2, acc1, acc2);
            float h2f;
            float o2 = cell_bn(acc1, acc2, bias2_s, gbuf, xh, stat_m, stat_r,
                               c2, g2v, be2v, m2v, h2f, lane, wav, quad, qm, bb, jj);
            h2buf[(1 - p) * BH + bb * HDIM + feat] = (__bf16)h2f;
            pmax = fmaxf(pmax, o2);
        }
        grid.sync();
    }

    pooled[bb * HDIM + feat] = pmax;
    grid.sync();

    // ================= final: logits + BCE loss (block 0 only) =========
    if (blk == 0) {
        const int b  = tid & 63;
        const int ch = tid >> 6;
        float s = 0.0f;
        for (int f = ch * 256; f < ch * 256 + 256; f++)
            s += pooled[b * HDIM + f] * fc_w[f];
        xh[ch * 64 + b] = s;
        __syncthreads();
        if (tid < 64) {
            float l = xh[0 * 64 + tid] + xh[1 * 64 + tid] + xh[2 * 64 + tid] +
                      xh[3 * 64 + tid] + fc_b[0];
            out[1 + tid] = l;
            float tval = tv[tid];
            float term = fmaxf(l, 0.0f) - l * tval + log1pf(expf(-fabsf(l)));
#pragma unroll
            for (int off = 32; off; off >>= 1) term += __shfl_xor(term, off);
            if (tid == 0) out[0] = term * (1.0f / 64.0f);
        }
    }
}

extern "C" void kernel_launch(void* const* d_in, const int* in_sizes, int n_in,
                              void* d_out, int out_size, void* d_ws, size_t ws_size,
                              hipStream_t stream) {
    const int*   x    = (const int*)d_in[0];
    const float* tv   = (const float*)d_in[1];
    const float* emb  = (const float*)d_in[2];
    const float* wih1 = (const float*)d_in[3];
    const float* whh1 = (const float*)d_in[4];
    const float* bih1 = (const float*)d_in[5];
    const float* bhh1 = (const float*)d_in[6];
    const float* g1   = (const float*)d_in[7];
    const float* be1  = (const float*)d_in[8];
    const float* wih2 = (const float*)d_in[9];
    const float* whh2 = (const float*)d_in[10];
    const float* bih2 = (const float*)d_in[11];
    const float* bhh2 = (const float*)d_in[12];
    const float* g2   = (const float*)d_in[13];
    const float* be2  = (const float*)d_in[14];
    const float* fcw  = (const float*)d_in[15];
    const float* fcb  = (const float*)d_in[16];
    const float* m1   = (const float*)d_in[17];
    const float* m2   = (const float*)d_in[18];

    char* w = (char*)d_ws;
    __bf16* h1buf  = (__bf16*)(w);                 // 2*64*1024*2 = 256 KB
    __bf16* h2buf  = (__bf16*)(w + 256 * 1024);    // 256 KB
    __bf16* o1buf  = (__bf16*)(w + 512 * 1024);    // 128 KB
    float*  pooled = (float*)(w + 640 * 1024);     // 256 KB
    float*  out    = (float*)d_out;

    // zero h1/h2 ping-pong buffers (initial hidden state = 0)
    hipMemsetAsync(d_ws, 0, 512 * 1024, stream);

    void* args[] = {&x, &tv, &emb, &wih1, &whh1, &bih1, &bhh1, &g1, &be1,
                    &wih2, &whh2, &bih2, &bhh2, &g2, &be2, &fcw, &fcb, &m1, &m2,
                    &h1buf, &h2buf, &o1buf, &pooled, &out};
    hipLaunchCooperativeKernel((void*)rnn_all, dim3(256), dim3(256), args, 0, stream);
}

// Round 2
// 37055.841 us; speedup vs baseline: 1.1607x; 1.1607x over previous
//
#include <hip/hip_runtime.h>

#define HDIM  1024
#define BDIM  64
#define TDIM  512
#define BH    (BDIM * HDIM)     // 65536 elems
#define WPAD  1032              // weight LDS row stride in bf16 (W%32 words == 4 -> balanced b128)
#define SLOTS 4                 // o1 ring slots (layer1 run-ahead bound)
#define NBLK  128               // blocks per layer group

typedef __bf16 bf16x8 __attribute__((ext_vector_type(8)));
typedef float  f32x4  __attribute__((ext_vector_type(4)));

__device__ __forceinline__ float sigf(float x) { return 1.0f / (1.0f + expf(-x)); }

__device__ __forceinline__ bf16x8 cvt8(const float* p) {
    const f32x4* q = (const f32x4*)p;
    f32x4 a = q[0], b = q[1];
    bf16x8 r;
    r[0] = (__bf16)a[0]; r[1] = (__bf16)a[1]; r[2] = (__bf16)a[2]; r[3] = (__bf16)a[3];
    r[4] = (__bf16)b[0]; r[5] = (__bf16)b[1]; r[6] = (__bf16)b[2]; r[7] = (__bf16)b[3];
    return r;
}

// acc1 += A1*Bih, acc2 += A2*Bhh over K=1024; one wave does a 16(batch)x16(gaterow) tile.
template <bool A1_F32>
__device__ __forceinline__ void dual_gemm(const void* a1p, const __bf16* a2p,
                                          const __bf16* b1p, const __bf16* b2p,
                                          f32x4& acc1, f32x4& acc2) {
#pragma unroll 8
    for (int ks = 0; ks < HDIM; ks += 32) {
        bf16x8 va;
        if constexpr (A1_F32)
            va = cvt8((const float*)a1p + ks);
        else
            va = *(const bf16x8*)((const __bf16*)a1p + ks);
        bf16x8 vb = *(const bf16x8*)(a2p + ks);
        bf16x8 wa = *(const bf16x8*)(b1p + ks);
        bf16x8 wb = *(const bf16x8*)(b2p + ks);
        acc1 = __builtin_amdgcn_mfma_f32_16x16x32_bf16(va, wa, acc1, 0, 0, 0);
        acc2 = __builtin_amdgcn_mfma_f32_16x16x32_bf16(vb, wb, acc2, 0, 0, 0);
    }
}

// ---- inter-block sync primitives (counter per step, zeroed by memset) ----
__device__ __forceinline__ void wait2(int* c1, int n1, int* c2, int n2) {
    if (threadIdx.x == 0) {
        if (c1) while (__hip_atomic_load(c1, __ATOMIC_RELAXED, __HIP_MEMORY_SCOPE_AGENT) < n1)
            __builtin_amdgcn_s_sleep(1);
        if (c2) while (__hip_atomic_load(c2, __ATOMIC_RELAXED, __HIP_MEMORY_SCOPE_AGENT) < n2)
            __builtin_amdgcn_s_sleep(1);
    }
    __syncthreads();
    __builtin_amdgcn_fence(__ATOMIC_ACQUIRE, "agent");   // all threads: inv stale caches
}

__device__ __forceinline__ void post(int* c) {
    __builtin_amdgcn_fence(__ATOMIC_RELEASE, "agent");   // all threads: flush my stores
    __syncthreads();
    if (threadIdx.x == 0)
        __hip_atomic_fetch_add(c, 1, __ATOMIC_RELAXED, __HIP_MEMORY_SCOPE_AGENT);
}

// gates -> LSTM cell -> BN -> mask. One thread = one (batch,feature) cell.
__device__ __forceinline__ float cell_bn(const f32x4& acc1, const f32x4& acc2,
                                         const float* bias_s, float* gbuf, float* xh,
                                         float* stat_m, float* stat_r,
                                         float& c, float gam, float bet, float msk,
                                         float& hout,
                                         int lane, int wv, int quad, int qm,
                                         int bt, int rt, int bb, int jj) {
    const float bv = bias_s[rt * 16 + qm];
#pragma unroll
    for (int r = 0; r < 4; r++)
        gbuf[(bt * 16 + quad * 4 + r) * 36 + rt * 16 + qm] = acc1[r] + acc2[r] + bv;
    __syncthreads();
    float gi = gbuf[bb * 36 + 0  + jj];
    float gf = gbuf[bb * 36 + 8  + jj];
    float gg = gbuf[bb * 36 + 16 + jj];
    float go = gbuf[bb * 36 + 24 + jj];
    c = sigf(gf) * c + sigf(gi) * tanhf(gg);
    float h = sigf(go) * tanhf(c);
    hout = h;
    xh[jj * 68 + bb] = h;
    __syncthreads();
    // BN stats: wave wv reduces feature wv over 64 batch rows
    float v = xh[wv * 68 + lane];
    float s1 = v, s2 = v * v;
#pragma unroll
    for (int off = 32; off; off >>= 1) {
        s1 += __shfl_xor(s1, off);
        s2 += __shfl_xor(s2, off);
    }
    if (lane == 0) {
        float m  = s1 * (1.0f / 64.0f);
        float va = s2 * (1.0f / 64.0f) - m * m;
        stat_m[wv] = m;
        stat_r[wv] = rsqrtf(va + 1e-5f);
    }
    __syncthreads();
    return ((h - stat_m[jj]) * stat_r[jj] * gam + bet) * msk;
}

// Pre-pass: xseq[t*64+b][k] = bf16(emb[x[b,t]][k])
__global__ void gather_emb(const int* __restrict__ x, const float* __restrict__ emb,
                           __bf16* __restrict__ xseq) {
    int row = blockIdx.x;            // t*64 + b
    int t = row >> 6, b = row & 63;
    int tok = x[b * TDIM + t];
    const float* src = emb + (size_t)tok * HDIM;
    __bf16* dst = xseq + (size_t)row * HDIM;
    for (int k = threadIdx.x; k < HDIM; k += 256) dst[k] = (__bf16)src[k];
}

__global__ void __launch_bounds__(512, 1) rnn_all(
    const int* __restrict__ x, const float* __restrict__ tv,
    const float* __restrict__ emb,
    const float* __restrict__ w_ih1, const float* __restrict__ w_hh1,
    const float* __restrict__ b_ih1, const float* __restrict__ b_hh1,
    const float* __restrict__ gamma1, const float* __restrict__ beta1,
    const float* __restrict__ w_ih2, const float* __restrict__ w_hh2,
    const float* __restrict__ b_ih2, const float* __restrict__ b_hh2,
    const float* __restrict__ gamma2, const float* __restrict__ beta2,
    const float* __restrict__ fc_w, const float* __restrict__ fc_b,
    const float* __restrict__ mask1, const float* __restrict__ mask2,
    const __bf16* __restrict__ xseq, int use_xseq,
    __bf16* __restrict__ h1buf, __bf16* __restrict__ h2buf,
    __bf16* __restrict__ o1buf, float* __restrict__ pooled,
    int* __restrict__ l1done, int* __restrict__ l2done, int* __restrict__ pooldone,
    float* __restrict__ out) {
    __shared__ __bf16 wih_s[32 * WPAD];
    __shared__ __bf16 whh_s[32 * WPAD];
    __shared__ float bias_s[32];
    __shared__ float gbuf[64 * 36];
    __shared__ float xh[8 * 68];
    __shared__ float stat_m[8], stat_r[8];

    const int tid   = threadIdx.x;
    const int layer = blockIdx.x & 1;     // 0: layer1 group, 1: layer2 group
    const int lb    = blockIdx.x >> 1;    // 0..127 within group
    const int fbase = lb * 8;

    const float* w_ih = layer ? w_ih2 : w_ih1;
    const float* w_hh = layer ? w_hh2 : w_hh1;
    const float* b_ih = layer ? b_ih2 : b_ih1;
    const float* b_hh = layer ? b_hh2 : b_hh1;
    const float* gam_ = layer ? gamma2 : gamma1;
    const float* bet_ = layer ? beta2  : beta1;
    const float* msk_ = layer ? mask2  : mask1;

    // ---- stage this block's 32 gate rows (gate-major, feature minor) into LDS
    for (int idx = tid; idx < 32 * HDIM; idx += 512) {
        int n = idx >> 10, k = idx & 1023;
        int row = (n >> 3) * HDIM + fbase + (n & 7);
        wih_s[n * WPAD + k] = (__bf16)w_ih[row * HDIM + k];
        whh_s[n * WPAD + k] = (__bf16)w_hh[row * HDIM + k];
    }
    if (tid < 32) {
        int row = (tid >> 3) * HDIM + fbase + (tid & 7);
        bias_s[tid] = b_ih[row] + b_hh[row];
    }
    __syncthreads();

    // ---- roles
    const int lane = tid & 63;
    const int wv   = tid >> 6;          // 0..7
    const int bt   = wv >> 1;           // batch tile 0..3
    const int rt   = wv & 1;            // gate-row tile 0..1
    const int qm   = lane & 15;
    const int quad = lane >> 4;
    const int arow = bt * 16 + qm;      // batch row for A loads
    const int k0q  = quad * 8;

    const __bf16* bwi = wih_s + (rt * 16 + qm) * WPAD + k0q;
    const __bf16* bwh = whh_s + (rt * 16 + qm) * WPAD + k0q;

    const int bb = tid >> 3, jj = tid & 7;
    const int feat = fbase + jj;
    const float gv = gam_[feat], bev = bet_[feat], mv = msk_[bb * HDIM + feat];
    float c = 0.0f, pmax = -1e30f;

    if (layer == 0) {
        // ===================== layer-1 group =====================
#pragma unroll 1
        for (int t = 0; t < TDIM; t++) {
            wait2(t >= 1 ? &l1done[t - 1] : nullptr, NBLK,
                  t >= SLOTS ? &l2done[t - SLOTS] : nullptr, NBLK);
            const __bf16* a2 = h1buf + (size_t)(t & 1) * BH + arow * HDIM + k0q;
            f32x4 acc1 = {0.f, 0.f, 0.f, 0.f}, acc2 = {0.f, 0.f, 0.f, 0.f};
            if (use_xseq) {
                const __bf16* a1 = xseq + ((size_t)t * 64 + arow) * HDIM + k0q;
                dual_gemm<false>(a1, a2, bwi, bwh, acc1, acc2);
            } else {
                const float* a1 = emb + (size_t)x[arow * TDIM + t] * HDIM + k0q;
                dual_gemm<true>(a1, a2, bwi, bwh, acc1, acc2);
            }
            float h;
            float o = cell_bn(acc1, acc2, bias_s, gbuf, xh, stat_m, stat_r,
                              c, gv, bev, mv, h, lane, wv, quad, qm, bt, rt, bb, jj);
            h1buf[(size_t)((t + 1) & 1) * BH + bb * HDIM + feat] = (__bf16)h;
            o1buf[(size_t)(t & (SLOTS - 1)) * BH + bb * HDIM + feat] = (__bf16)o;
            post(&l1done[t]);
        }
    } else {
        // ===================== layer-2 group =====================
#pragma unroll 1
        for (int t = 0; t < TDIM; t++) {
            wait2(&l1done[t], NBLK,
                  t >= 1 ? &l2done[t - 1] : nullptr, NBLK);
            const __bf16* a1 = o1buf + (size_t)(t & (SLOTS - 1)) * BH + arow * HDIM + k0q;
            const __bf16* a2 = h2buf + (size_t)(t & 1) * BH + arow * HDIM + k0q;
            f32x4 acc1 = {0.f, 0.f, 0.f, 0.f}, acc2 = {0.f, 0.f, 0.f, 0.f};
            dual_gemm<false>(a1, a2, bwi, bwh, acc1, acc2);
            float h;
            float o = cell_bn(acc1, acc2, bias_s, gbuf, xh, stat_m, stat_r,
                              c, gv, bev, mv, h, lane, wv, quad, qm, bt, rt, bb, jj);
            h2buf[(size_t)((t + 1) & 1) * BH + bb * HDIM + feat] = (__bf16)h;
            pmax = fmaxf(pmax, o);
            post(&l2done[t]);
        }
        pooled[bb * HDIM + feat] = pmax;
        post(pooldone);

        if (lb == 0) {
            // ============== FC + BCE loss (one block) ==============
            wait2(pooldone, NBLK, nullptr, 0);
            int b  = wv * 8 + (lane >> 3);
            int l8 = lane & 7;
            float s = 0.0f;
            for (int f = l8 * 128; f < l8 * 128 + 128; f++)
                s += pooled[b * HDIM + f] * fc_w[f];
            s += __shfl_xor(s, 1); s += __shfl_xor(s, 2); s += __shfl_xor(s, 4);
            float logit = s + fc_b[0];
            if (l8 == 0) {
                out[1 + b] = logit;
                gbuf[b] = fmaxf(logit, 0.0f) - logit * tv[b] + log1pf(expf(-fabsf(logit)));
            }
            __syncthreads();
            if (tid < 64) {
                float term = gbuf[tid];
#pragma unroll
                for (int off = 32; off; off >>= 1) term += __shfl_xor(term, off);
                if (tid == 0) out[0] = term * (1.0f / 64.0f);
            }
        }
    }
}

extern "C" void kernel_launch(void* const* d_in, const int* in_sizes, int n_in,
                              void* d_out, int out_size, void* d_ws, size_t ws_size,
                              hipStream_t stream) {
    const int*   x    = (const int*)d_in[0];
    const float* tv   = (const float*)d_in[1];
    const float* emb  = (const float*)d_in[2];
    const float* wih1 = (const float*)d_in[3];
    const float* whh1 = (const float*)d_in[4];
    const float* bih1 = (const float*)d_in[5];
    const float* bhh1 = (const float*)d_in[6];
    const float* g1   = (const float*)d_in[7];
    const float* be1  = (const float*)d_in[8];
    const float* wih2 = (const float*)d_in[9];
    const float* whh2 = (const float*)d_in[10];
    const float* bih2 = (const float*)d_in[11];
    const float* bhh2 = (const float*)d_in[12];
    const float* g2   = (const float*)d_in[13];
    const float* be2  = (const float*)d_in[14];
    const float* fcw  = (const float*)d_in[15];
    const float* fcb  = (const float*)d_in[16];
    const float* m1   = (const float*)d_in[17];
    const float* m2   = (const float*)d_in[18];

    char* w = (char*)d_ws;
    int*    l1done   = (int*)(w + 0);                 // 2048 B
    int*    l2done   = (int*)(w + 2048);              // 2048 B
    int*    pooldone = (int*)(w + 4096);              // 4 B (pad to 8192)
    __bf16* h1buf    = (__bf16*)(w + 8192);           // 256 KB (2 slots)
    __bf16* h2buf    = (__bf16*)(w + 8192 + 262144);  // 256 KB
    __bf16* o1buf    = (__bf16*)(w + 8192 + 524288);  // 512 KB (4 slots)
    float*  pooled   = (float*)(w + 8192 + 1048576);  // 256 KB
    __bf16* xseq     = (__bf16*)(w + 8192 + 1310720); // 64 MB optional
    float*  out      = (float*)d_out;

    size_t need_xseq = (size_t)8192 + 1310720 + (size_t)TDIM * BDIM * HDIM * 2;
    int use_xseq = (ws_size >= need_xseq) ? 1 : 0;

    // zero counters + h1/h2 initial state (ws is poisoned 0xAA before each call)
    hipMemsetAsync(d_ws, 0, 8192 + 524288, stream);

    if (use_xseq)
        gather_emb<<<dim3(TDIM * BDIM), dim3(256), 0, stream>>>(x, emb, xseq);

    void* args[] = {&x, &tv, &emb, &wih1, &whh1, &bih1, &bhh1, &g1, &be1,
                    &wih2, &whh2, &bih2, &bhh2, &g2, &be2, &fcw, &fcb, &m1, &m2,
                    &xseq, &use_xseq,
                    &h1buf, &h2buf, &o1buf, &pooled,
                    &l1done, &l2done, &pooldone, &out};
    hipLaunchCooperativeKernel((void*)rnn_all, dim3(256), dim3(512), args, 0, stream);
}

// Round 3
// 16952.171 us; speedup vs baseline: 2.5371x; 2.1859x over previous
//
#include <hip/hip_runtime.h>

#define HDIM  1024
#define BDIM  64
#define TDIM  512
#define BH    (BDIM * HDIM)     // 65536 elems
#define WPAD  1032              // weight LDS row stride in bf16
#define SLOTS 4                 // o1 ring slots (layer1 run-ahead bound)
#define NBLK  128               // blocks per layer group

typedef __bf16 bf16x8 __attribute__((ext_vector_type(8)));
typedef float  f32x4  __attribute__((ext_vector_type(4)));

__device__ __forceinline__ float sigf(float x) { return 1.0f / (1.0f + expf(-x)); }

__device__ __forceinline__ bf16x8 cvt8(const float* p) {
    const f32x4* q = (const f32x4*)p;
    f32x4 a = q[0], b = q[1];
    bf16x8 r;
    r[0] = (__bf16)a[0]; r[1] = (__bf16)a[1]; r[2] = (__bf16)a[2]; r[3] = (__bf16)a[3];
    r[4] = (__bf16)b[0]; r[5] = (__bf16)b[1]; r[6] = (__bf16)b[2]; r[7] = (__bf16)b[3];
    return r;
}

// acc += A * B over K=1024; one wave does a 16(batch) x 16(gaterow) tile.
template <bool A_F32>
__device__ __forceinline__ void gemm1(const void* ap, const __bf16* bp, f32x4& acc) {
#pragma unroll 8
    for (int ks = 0; ks < HDIM; ks += 32) {
        bf16x8 va;
        if constexpr (A_F32)
            va = cvt8((const float*)ap + ks);
        else
            va = *(const bf16x8*)((const __bf16*)ap + ks);
        bf16x8 wa = *(const bf16x8*)(bp + ks);
        acc = __builtin_amdgcn_mfma_f32_16x16x32_bf16(va, wa, acc, 0, 0, 0);
    }
}

// ---- inter-block sync: flag counters live at MALL (sc1), no L2 cache maintenance
__device__ __forceinline__ void spin(const int* c, int n) {
    if (threadIdx.x == 0)
        while (__hip_atomic_load(c, __ATOMIC_RELAXED, __HIP_MEMORY_SCOPE_AGENT) < n)
            __builtin_amdgcn_s_sleep(1);
    __syncthreads();
}
__device__ __forceinline__ void acq() {
    __builtin_amdgcn_fence(__ATOMIC_ACQUIRE, "agent");   // buffer_inv (no wbl2)
}
__device__ __forceinline__ void post(int* c) {
    asm volatile("s_waitcnt vmcnt(0)" ::: "memory");     // my sc1 stores reached MALL
    __syncthreads();                                     // all waves' stores done
    if (threadIdx.x == 0)
        __hip_atomic_fetch_add(c, 1, __ATOMIC_RELAXED, __HIP_MEMORY_SCOPE_AGENT);
}

// packed bf16-pair store that bypasses L2 (write-through to MALL)
__device__ __forceinline__ void store_pair(__bf16* base, int idx_even, float v, int jj) {
    unsigned bits = (unsigned)__builtin_bit_cast(unsigned short, (__bf16)v);
    unsigned hi = __shfl_down(bits, 1);
    if ((jj & 1) == 0)
        __hip_atomic_store((unsigned*)(base + idx_even), bits | (hi << 16),
                           __ATOMIC_RELAXED, __HIP_MEMORY_SCOPE_AGENT);
}

// gates -> LSTM cell -> BN -> mask. One thread = one (batch,feature) cell.
__device__ __forceinline__ float cell_bn(const f32x4& acc1, const f32x4& acc2,
                                         const float* bias_s, float* gbuf, float* xh,
                                         float* stat_m, float* stat_r,
                                         float& c, float gam, float bet, float msk,
                                         float& hout,
                                         int lane, int wv, int quad, int qm,
                                         int bt, int rt, int bb, int jj) {
    const float bv = bias_s[rt * 16 + qm];
#pragma unroll
    for (int r = 0; r < 4; r++)
        gbuf[(bt * 16 + quad * 4 + r) * 36 + rt * 16 + qm] = acc1[r] + acc2[r] + bv;
    __syncthreads();
    float gi = gbuf[bb * 36 + 0  + jj];
    float gf = gbuf[bb * 36 + 8  + jj];
    float gg = gbuf[bb * 36 + 16 + jj];
    float go = gbuf[bb * 36 + 24 + jj];
    c = sigf(gf) * c + sigf(gi) * tanhf(gg);
    float h = sigf(go) * tanhf(c);
    hout = h;
    xh[jj * 68 + bb] = h;
    __syncthreads();
    float v = xh[wv * 68 + lane];
    float s1 = v, s2 = v * v;
#pragma unroll
    for (int off = 32; off; off >>= 1) {
        s1 += __shfl_xor(s1, off);
        s2 += __shfl_xor(s2, off);
    }
    if (lane == 0) {
        float m  = s1 * (1.0f / 64.0f);
        float va = s2 * (1.0f / 64.0f) - m * m;
        stat_m[wv] = m;
        stat_r[wv] = rsqrtf(va + 1e-5f);
    }
    __syncthreads();
    return ((h - stat_m[jj]) * stat_r[jj] * gam + bet) * msk;
}

// Pre-pass: xseq[t*64+b][k] = bf16(emb[x[b,t]][k])
__global__ void gather_emb(const int* __restrict__ x, const float* __restrict__ emb,
                           __bf16* __restrict__ xseq) {
    int row = blockIdx.x;            // t*64 + b
    int t = row >> 6, b = row & 63;
    int tok = x[b * TDIM + t];
    const float* src = emb + (size_t)tok * HDIM;
    __bf16* dst = xseq + (size_t)row * HDIM;
    for (int k = threadIdx.x; k < HDIM; k += 256) dst[k] = (__bf16)src[k];
}

__global__ void __launch_bounds__(512, 1) rnn_all(
    const int* __restrict__ x, const float* __restrict__ tv,
    const float* __restrict__ emb,
    const float* __restrict__ w_ih1, const float* __restrict__ w_hh1,
    const float* __restrict__ b_ih1, const float* __restrict__ b_hh1,
    const float* __restrict__ gamma1, const float* __restrict__ beta1,
    const float* __restrict__ w_ih2, const float* __restrict__ w_hh2,
    const float* __restrict__ b_ih2, const float* __restrict__ b_hh2,
    const float* __restrict__ gamma2, const float* __restrict__ beta2,
    const float* __restrict__ fc_w, const float* __restrict__ fc_b,
    const float* __restrict__ mask1, const float* __restrict__ mask2,
    const __bf16* __restrict__ xseq, int use_xseq,
    __bf16* __restrict__ h1buf, __bf16* __restrict__ h2buf,
    __bf16* __restrict__ o1buf, float* __restrict__ pooled,
    int* __restrict__ l1done, int* __restrict__ l2done, int* __restrict__ pooldone,
    float* __restrict__ out) {
    __shared__ __bf16 wih_s[32 * WPAD];
    __shared__ __bf16 whh_s[32 * WPAD];
    __shared__ float bias_s[32];
    __shared__ float gbuf[64 * 36];
    __shared__ float xh[8 * 68];
    __shared__ float stat_m[8], stat_r[8];

    const int tid   = threadIdx.x;
    const int layer = blockIdx.x & 1;
    const int lb    = blockIdx.x >> 1;
    const int fbase = lb * 8;

    const float* w_ih = layer ? w_ih2 : w_ih1;
    const float* w_hh = layer ? w_hh2 : w_hh1;
    const float* b_ih = layer ? b_ih2 : b_ih1;
    const float* b_hh = layer ? b_hh2 : b_hh1;
    const float* gam_ = layer ? gamma2 : gamma1;
    const float* bet_ = layer ? beta2  : beta1;
    const float* msk_ = layer ? mask2  : mask1;

    for (int idx = tid; idx < 32 * HDIM; idx += 512) {
        int n = idx >> 10, k = idx & 1023;
        int row = (n >> 3) * HDIM + fbase + (n & 7);
        wih_s[n * WPAD + k] = (__bf16)w_ih[row * HDIM + k];
        whh_s[n * WPAD + k] = (__bf16)w_hh[row * HDIM + k];
    }
    if (tid < 32) {
        int row = (tid >> 3) * HDIM + fbase + (tid & 7);
        bias_s[tid] = b_ih[row] + b_hh[row];
    }
    __syncthreads();

    const int lane = tid & 63;
    const int wv   = tid >> 6;          // 0..7
    const int bt   = wv >> 1;           // batch tile 0..3
    const int rt   = wv & 1;            // gate-row tile 0..1
    const int qm   = lane & 15;
    const int quad = lane >> 4;
    const int arow = bt * 16 + qm;
    const int k0q  = quad * 8;

    const __bf16* bwi = wih_s + (rt * 16 + qm) * WPAD + k0q;
    const __bf16* bwh = whh_s + (rt * 16 + qm) * WPAD + k0q;

    const int bb = tid >> 3, jj = tid & 7;
    const int feat = fbase + jj;
    const float gv = gam_[feat], bev = bet_[feat], mv = msk_[bb * HDIM + feat];
    float c = 0.0f, pmax = -1e30f;

    if (layer == 0) {
        // ===================== layer-1 group =====================
#pragma unroll 1
        for (int t = 0; t < TDIM; t++) {
            // x-GEMM: no cross-block dependency -> off the critical path
            f32x4 acc1 = {0.f, 0.f, 0.f, 0.f};
            if (use_xseq)
                gemm1<false>(xseq + ((size_t)t * 64 + arow) * HDIM + k0q, bwi, acc1);
            else
                gemm1<true>(emb + (size_t)x[arow * TDIM + t] * HDIM + k0q, bwi, acc1);
            if (t >= SLOTS) spin(&l2done[t - SLOTS], NBLK);   // o1 ring throttle
            if (t >= 1)     spin(&l1done[t - 1], NBLK);       // h1 ready
            acq();
            f32x4 acc2 = {0.f, 0.f, 0.f, 0.f};
            gemm1<false>(h1buf + (size_t)(t & 1) * BH + arow * HDIM + k0q, bwh, acc2);
            float h;
            float o = cell_bn(acc1, acc2, bias_s, gbuf, xh, stat_m, stat_r,
                              c, gv, bev, mv, h, lane, wv, quad, qm, bt, rt, bb, jj);
            if (!(jj & 1)) {}  // (store_pair handles lane pairing internally)
            store_pair(h1buf + (size_t)((t + 1) & 1) * BH, bb * HDIM + (feat & ~1), h, jj);
            store_pair(o1buf + (size_t)(t & (SLOTS - 1)) * BH, bb * HDIM + (feat & ~1), o, jj);
            post(&l1done[t]);
        }
    } else {
        // ===================== layer-2 group =====================
#pragma unroll 1
        for (int t = 0; t < TDIM; t++) {
            if (t >= 1) spin(&l2done[t - 1], NBLK);   // h2 ready
            spin(&l1done[t], NBLK);                   // o1[t] ready
            acq();
            f32x4 acc1 = {0.f, 0.f, 0.f, 0.f}, acc2 = {0.f, 0.f, 0.f, 0.f};
            gemm1<false>(o1buf + (size_t)(t & (SLOTS - 1)) * BH + arow * HDIM + k0q, bwi, acc1);
            gemm1<false>(h2buf + (size_t)(t & 1) * BH + arow * HDIM + k0q, bwh, acc2);
            float h;
            float o = cell_bn(acc1, acc2, bias_s, gbuf, xh, stat_m, stat_r,
                              c, gv, bev, mv, h, lane, wv, quad, qm, bt, rt, bb, jj);
            store_pair(h2buf + (size_t)((t + 1) & 1) * BH, bb * HDIM + (feat & ~1), h, jj);
            pmax = fmaxf(pmax, o);
            post(&l2done[t]);
        }
        __hip_atomic_store(&pooled[bb * HDIM + feat], pmax,
                           __ATOMIC_RELAXED, __HIP_MEMORY_SCOPE_AGENT);
        post(pooldone);

        if (lb == 0) {
            // ============== FC + BCE loss (one block) ==============
            spin(pooldone, NBLK);
            acq();
            int b  = wv * 8 + (lane >> 3);
            int l8 = lane & 7;
            float s = 0.0f;
            for (int f = l8 * 128; f < l8 * 128 + 128; f++)
                s += pooled[b * HDIM + f] * fc_w[f];
            s += __shfl_xor(s, 1); s += __shfl_xor(s, 2); s += __shfl_xor(s, 4);
            float logit = s + fc_b[0];
            if (l8 == 0) {
                out[1 + b] = logit;
                gbuf[b] = fmaxf(logit, 0.0f) - logit * tv[b] + log1pf(expf(-fabsf(logit)));
            }
            __syncthreads();
            if (tid < 64) {
                float term = gbuf[tid];
#pragma unroll
                for (int off = 32; off; off >>= 1) term += __shfl_xor(term, off);
                if (tid == 0) out[0] = term * (1.0f / 64.0f);
            }
        }
    }
}

extern "C" void kernel_launch(void* const* d_in, const int* in_sizes, int n_in,
                              void* d_out, int out_size, void* d_ws, size_t ws_size,
                              hipStream_t stream) {
    const int*   x    = (const int*)d_in[0];
    const float* tv   = (const float*)d_in[1];
    const float* emb  = (const float*)d_in[2];
    const float* wih1 = (const float*)d_in[3];
    const float* whh1 = (const float*)d_in[4];
    const float* bih1 = (const float*)d_in[5];
    const float* bhh1 = (const float*)d_in[6];
    const float* g1   = (const float*)d_in[7];
    const float* be1  = (const float*)d_in[8];
    const float* wih2 = (const float*)d_in[9];
    const float* whh2 = (const float*)d_in[10];
    const float* bih2 = (const float*)d_in[11];
    const float* bhh2 = (const float*)d_in[12];
    const float* g2   = (const float*)d_in[13];
    const float* be2  = (const float*)d_in[14];
    const float* fcw  = (const float*)d_in[15];
    const float* fcb  = (const float*)d_in[16];
    const float* m1   = (const float*)d_in[17];
    const float* m2   = (const float*)d_in[18];

    char* w = (char*)d_ws;
    int*    l1done   = (int*)(w + 0);                 // 2048 B
    int*    l2done   = (int*)(w + 2048);              // 2048 B
    int*    pooldone = (int*)(w + 4096);              // 4 B (pad to 8192)
    __bf16* h1buf    = (__bf16*)(w + 8192);           // 256 KB (2 slots)
    __bf16* h2buf    = (__bf16*)(w + 8192 + 262144);  // 256 KB
    __bf16* o1buf    = (__bf16*)(w + 8192 + 524288);  // 512 KB (4 slots)
    float*  pooled   = (float*)(w + 8192 + 1048576);  // 256 KB
    __bf16* xseq     = (__bf16*)(w + 8192 + 1310720); // 64 MB optional
    float*  out      = (float*)d_out;

    size_t need_xseq = (size_t)8192 + 1310720 + (size_t)TDIM * BDIM * HDIM * 2;
    int use_xseq = (ws_size >= need_xseq) ? 1 : 0;

    hipMemsetAsync(d_ws, 0, 8192 + 524288, stream);

    if (use_xseq)
        gather_emb<<<dim3(TDIM * BDIM), dim3(256), 0, stream>>>(x, emb, xseq);

    void* args[] = {&x, &tv, &emb, &wih1, &whh1, &bih1, &bhh1, &g1, &be1,
                    &wih2, &whh2, &bih2, &bhh2, &g2, &be2, &fcw, &fcb, &m1, &m2,
                    &xseq, &use_xseq,
                    &h1buf, &h2buf, &o1buf, &pooled,
                    &l1done, &l2done, &pooldone, &out};
    hipLaunchCooperativeKernel((void*)rnn_all, dim3(256), dim3(512), args, 0, stream);
}

// Round 4
// 6854.659 us; speedup vs baseline: 6.2745x; 2.4731x over previous
//
#include <hip/hip_runtime.h>

#define HDIM  1024
#define BDIM  64
#define TDIM  512
#define BH    (BDIM * HDIM)     // 65536 elems
#define WPAD  1032              // weight LDS row stride in bf16
#define SLOTS 4                 // o1 ring slots
#define NGRP  8                 // arrival sub-groups per layer
#define NARR  8                 // global counter target (one per sub-group)

typedef __bf16 bf16x8 __attribute__((ext_vector_type(8)));
typedef float  f32x4  __attribute__((ext_vector_type(4)));

#define MFMA(a, b, c) __builtin_amdgcn_mfma_f32_16x16x32_bf16(a, b, c, 0, 0, 0)

// MALL-coherent 16B load (bypasses L1+L2): no fences needed anywhere.
#define GL(dst, p, off) \
    asm volatile("global_load_dwordx4 %0, %1, off offset:" off " sc0 sc1" \
                 : "=v"(dst) : "v"(p) : "memory")
#define GL16(f, p) do { \
    GL(f[0],  p, "0");   GL(f[1],  p, "64");  GL(f[2],  p, "128"); GL(f[3],  p, "192"); \
    GL(f[4],  p, "256"); GL(f[5],  p, "320"); GL(f[6],  p, "384"); GL(f[7],  p, "448"); \
    GL(f[8],  p, "512"); GL(f[9],  p, "576"); GL(f[10], p, "640"); GL(f[11], p, "704"); \
    GL(f[12], p, "768"); GL(f[13], p, "832"); GL(f[14], p, "896"); GL(f[15], p, "960"); \
} while (0)
#define WAITV() asm volatile("s_waitcnt vmcnt(0)" ::: "memory")

__device__ __forceinline__ float sigf(float x) { return 1.0f / (1.0f + expf(-x)); }

__device__ __forceinline__ bf16x8 cvt8(const float* p) {
    const f32x4* q = (const f32x4*)p;
    f32x4 a = q[0], b = q[1];
    bf16x8 r;
    r[0] = (__bf16)a[0]; r[1] = (__bf16)a[1]; r[2] = (__bf16)a[2]; r[3] = (__bf16)a[3];
    r[4] = (__bf16)b[0]; r[5] = (__bf16)b[1]; r[6] = (__bf16)b[2]; r[7] = (__bf16)b[3];
    return r;
}

// ---- sync primitives: all counters live at MALL; fan-in <= 16 per line ----
__device__ __forceinline__ void spin(const int* c, int n) {
    if (threadIdx.x == 0)
        while (__hip_atomic_load(c, __ATOMIC_RELAXED, __HIP_MEMORY_SCOPE_AGENT) < n)
            __builtin_amdgcn_s_sleep(1);
    __syncthreads();
}
__device__ __forceinline__ void arrive(int* sub, int* glob) {
    WAITV();                 // each wave: my sc0sc1 stores reached MALL
    __syncthreads();         // whole block's stores done
    if (threadIdx.x == 0) {
        int old = __hip_atomic_fetch_add(sub, 1, __ATOMIC_RELAXED, __HIP_MEMORY_SCOPE_AGENT);
        if (old == 15)       // last of my 16-block sub-group
            __hip_atomic_fetch_add(glob, 1, __ATOMIC_RELAXED, __HIP_MEMORY_SCOPE_AGENT);
    }
}

// packed bf16-pair store, write-through to MALL
__device__ __forceinline__ void store_pair(__bf16* base, int idx_even, float v, int jj) {
    unsigned bits = (unsigned)__builtin_bit_cast(unsigned short, (__bf16)v);
    unsigned hi = __shfl_down(bits, 1);
    if ((jj & 1) == 0)
        __hip_atomic_store((unsigned*)(base + idx_even), bits | (hi << 16),
                           __ATOMIC_RELAXED, __HIP_MEMORY_SCOPE_AGENT);
}

// Pre-pass: xseq[t*64+b][k] = bf16(emb[x[b,t]][k])
__global__ void gather_emb(const int* __restrict__ x, const float* __restrict__ emb,
                           __bf16* __restrict__ xseq) {
    int row = blockIdx.x;            // t*64 + b
    int t = row >> 6, b = row & 63;
    int tok = x[b * TDIM + t];
    const float* src = emb + (size_t)tok * HDIM;
    __bf16* dst = xseq + (size_t)row * HDIM;
    for (int k = threadIdx.x; k < HDIM; k += 256) dst[k] = (__bf16)src[k];
}

__global__ void __launch_bounds__(512, 1) rnn_all(
    const int* __restrict__ x, const float* __restrict__ tv,
    const float* __restrict__ emb,
    const float* __restrict__ w_ih1, const float* __restrict__ w_hh1,
    const float* __restrict__ b_ih1, const float* __restrict__ b_hh1,
    const float* __restrict__ gamma1, const float* __restrict__ beta1,
    const float* __restrict__ w_ih2, const float* __restrict__ w_hh2,
    const float* __restrict__ b_ih2, const float* __restrict__ b_hh2,
    const float* __restrict__ gamma2, const float* __restrict__ beta2,
    const float* __restrict__ fc_w, const float* __restrict__ fc_b,
    const float* __restrict__ mask1, const float* __restrict__ mask2,
    const __bf16* __restrict__ xseq, int use_xseq,
    int* __restrict__ l1g, int* __restrict__ l2g,
    int* __restrict__ l1s, int* __restrict__ l2s,
    int* __restrict__ poolg, int* __restrict__ pools,
    __bf16* __restrict__ h1buf, __bf16* __restrict__ h2buf,
    __bf16* __restrict__ o1buf, float* __restrict__ pooled,
    float* __restrict__ out) {
    __shared__ __bf16 wih_s[32 * WPAD];
    __shared__ __bf16 whh_s[32 * WPAD];
    __shared__ float bias_s[32];
    __shared__ float gbuf[64 * 36];
    __shared__ float xh[8 * 68];
    __shared__ float stat_m[8], stat_r[8];

    const int tid   = threadIdx.x;
    const int layer = blockIdx.x & 1;
    const int lb    = blockIdx.x >> 1;      // 0..127 within layer group
    const int grp   = lb >> 4;              // 0..7 arrival sub-group
    const int fbase = lb * 8;

    const float* w_ih = layer ? w_ih2 : w_ih1;
    const float* w_hh = layer ? w_hh2 : w_hh1;
    const float* b_ih = layer ? b_ih2 : b_ih1;
    const float* b_hh = layer ? b_hh2 : b_hh1;
    const float* gam_ = layer ? gamma2 : gamma1;
    const float* bet_ = layer ? beta2  : beta1;
    const float* msk_ = layer ? mask2  : mask1;

    for (int idx = tid; idx < 32 * HDIM; idx += 512) {
        int n = idx >> 10, k = idx & 1023;
        int row = (n >> 3) * HDIM + fbase + (n & 7);
        wih_s[n * WPAD + k] = (__bf16)w_ih[row * HDIM + k];
        whh_s[n * WPAD + k] = (__bf16)w_hh[row * HDIM + k];
    }
    if (tid < 32) {
        int row = (tid >> 3) * HDIM + fbase + (tid & 7);
        bias_s[tid] = b_ih[row] + b_hh[row];
    }
    __syncthreads();

    // roles: wave = (batch-tile, K-half); each block reads each A-byte once
    const int lane = tid & 63;
    const int wv   = tid >> 6;          // 0..7
    const int bt   = wv & 3;            // batch tile
    const int kh   = wv >> 2;           // K half (0: k<512, 1: k>=512)
    const int qm   = lane & 15;
    const int quad = lane >> 4;
    const int arow = bt * 16 + qm;
    const int kbase = kh * 512 + quad * 8;

    const __bf16* bwi0 = wih_s + qm * WPAD + kbase;
    const __bf16* bwi1 = wih_s + (16 + qm) * WPAD + kbase;
    const __bf16* bwh0 = whh_s + qm * WPAD + kbase;
    const __bf16* bwh1 = whh_s + (16 + qm) * WPAD + kbase;

    const int bb = tid >> 3, jj = tid & 7;
    const int feat = fbase + jj;
    const float gv = gam_[feat], bev = bet_[feat], mv = msk_[bb * HDIM + feat];
    float c = 0.0f, pmax = -1e30f;

#pragma unroll 1
    for (int t = 0; t < TDIM; t++) {
        f32x4 ax0 = {0.f,0.f,0.f,0.f}, ax1 = {0.f,0.f,0.f,0.f};
        f32x4 ah0 = {0.f,0.f,0.f,0.f}, ah1 = {0.f,0.f,0.f,0.f};
        bf16x8 fh[16];

        if (layer == 0) {
            // ---- x-GEMM off the critical path (normal cached loads) ----
            if (use_xseq) {
                const __bf16* a = xseq + ((size_t)t * 64 + arow) * HDIM + kbase;
#pragma unroll 4
                for (int i = 0; i < 16; i++) {
                    bf16x8 va = *(const bf16x8*)(a + i * 32);
                    ax0 = MFMA(va, *(const bf16x8*)(bwi0 + i * 32), ax0);
                    ax1 = MFMA(va, *(const bf16x8*)(bwi1 + i * 32), ax1);
                }
            } else {
                const float* a = emb + (size_t)x[arow * TDIM + t] * HDIM + kbase;
#pragma unroll 4
                for (int i = 0; i < 16; i++) {
                    bf16x8 va = cvt8(a + i * 32);
                    ax0 = MFMA(va, *(const bf16x8*)(bwi0 + i * 32), ax0);
                    ax1 = MFMA(va, *(const bf16x8*)(bwi1 + i * 32), ax1);
                }
            }
            if (t >= SLOTS) spin(l2g + (t - SLOTS) * 16, NARR);  // o1 ring free
            if (t >= 1)     spin(l1g + (t - 1) * 16, NARR);      // h1 ready
            const __bf16* ph = h1buf + (size_t)(t & 1) * BH + arow * HDIM + kbase;
            GL16(fh, ph);
            WAITV();
#pragma unroll
            for (int i = 0; i < 16; i++) {
                ah0 = MFMA(fh[i], *(const bf16x8*)(bwh0 + i * 32), ah0);
                ah1 = MFMA(fh[i], *(const bf16x8*)(bwh1 + i * 32), ah1);
            }
        } else {
            if (t >= 1) spin(l2g + (t - 1) * 16, NARR);          // h2 ready
            spin(l1g + t * 16, NARR);                            // o1[t] ready
            bf16x8 fo[16];
            const __bf16* po = o1buf + (size_t)(t & (SLOTS - 1)) * BH + arow * HDIM + kbase;
            const __bf16* ph = h2buf + (size_t)(t & 1) * BH + arow * HDIM + kbase;
            GL16(fo, po);
            GL16(fh, ph);
            WAITV();
#pragma unroll
            for (int i = 0; i < 16; i++) {
                ax0 = MFMA(fo[i], *(const bf16x8*)(bwi0 + i * 32), ax0);
                ax1 = MFMA(fo[i], *(const bf16x8*)(bwi1 + i * 32), ax1);
                ah0 = MFMA(fh[i], *(const bf16x8*)(bwh0 + i * 32), ah0);
                ah1 = MFMA(fh[i], *(const bf16x8*)(bwh1 + i * 32), ah1);
            }
        }

        // ---- combine K-halves in LDS (two-pass), add bias ----
        if (kh == 0) {
#pragma unroll
            for (int r = 0; r < 4; r++) {
                int row = (bt * 16 + quad * 4 + r) * 36;
                gbuf[row + qm]      = ax0[r] + ah0[r] + bias_s[qm];
                gbuf[row + 16 + qm] = ax1[r] + ah1[r] + bias_s[16 + qm];
            }
        }
        __syncthreads();
        if (kh == 1) {
#pragma unroll
            for (int r = 0; r < 4; r++) {
                int row = (bt * 16 + quad * 4 + r) * 36;
                gbuf[row + qm]      += ax0[r] + ah0[r];
                gbuf[row + 16 + qm] += ax1[r] + ah1[r];
            }
        }
        __syncthreads();

        // ---- LSTM cell + BN + mask: one thread per (batch,feature) ----
        float gi = gbuf[bb * 36 + jj];
        float gf = gbuf[bb * 36 + 8 + jj];
        float gg = gbuf[bb * 36 + 16 + jj];
        float go = gbuf[bb * 36 + 24 + jj];
        c = sigf(gf) * c + sigf(gi) * tanhf(gg);
        float h = sigf(go) * tanhf(c);
        xh[jj * 68 + bb] = h;
        __syncthreads();
        float v = xh[wv * 68 + lane];
        float s1 = v, s2 = v * v;
#pragma unroll
        for (int off = 32; off; off >>= 1) {
            s1 += __shfl_xor(s1, off);
            s2 += __shfl_xor(s2, off);
        }
        if (lane == 0) {
            float m  = s1 * (1.0f / 64.0f);
            float va = s2 * (1.0f / 64.0f) - m * m;
            stat_m[wv] = m;
            stat_r[wv] = rsqrtf(va + 1e-5f);
        }
        __syncthreads();
        float o = ((h - stat_m[jj]) * stat_r[jj] * gv + bev) * mv;

        if (layer == 0) {
            store_pair(h1buf + (size_t)((t + 1) & 1) * BH, bb * HDIM + (feat & ~1), h, jj);
            store_pair(o1buf + (size_t)(t & (SLOTS - 1)) * BH, bb * HDIM + (feat & ~1), o, jj);
            arrive(l1s + (t * NGRP + grp) * 16, l1g + t * 16);
        } else {
            store_pair(h2buf + (size_t)((t + 1) & 1) * BH, bb * HDIM + (feat & ~1), h, jj);
            pmax = fmaxf(pmax, o);
            arrive(l2s + (t * NGRP + grp) * 16, l2g + t * 16);
        }
    }

    if (layer == 1) {
        __hip_atomic_store(&pooled[bb * HDIM + feat], pmax,
                           __ATOMIC_RELAXED, __HIP_MEMORY_SCOPE_AGENT);
        arrive(pools + grp * 16, poolg);

        if (lb == 0) {
            // ============== FC + BCE loss (one block) ==============
            spin(poolg, NARR);
            __builtin_amdgcn_fence(__ATOMIC_ACQUIRE, "agent");   // one inv, off hot loop
            int b  = wv * 8 + (lane >> 3);
            int l8 = lane & 7;
            float s = 0.0f;
            for (int f = l8 * 128; f < l8 * 128 + 128; f++)
                s += pooled[b * HDIM + f] * fc_w[f];
            s += __shfl_xor(s, 1); s += __shfl_xor(s, 2); s += __shfl_xor(s, 4);
            float logit = s + fc_b[0];
            if (l8 == 0) {
                out[1 + b] = logit;
                gbuf[b] = fmaxf(logit, 0.0f) - logit * tv[b] + log1pf(expf(-fabsf(logit)));
            }
            __syncthreads();
            if (tid < 64) {
                float term = gbuf[tid];
#pragma unroll
                for (int off = 32; off; off >>= 1) term += __shfl_xor(term, off);
                if (tid == 0) out[0] = term * (1.0f / 64.0f);
            }
        }
    }
}

extern "C" void kernel_launch(void* const* d_in, const int* in_sizes, int n_in,
                              void* d_out, int out_size, void* d_ws, size_t ws_size,
                              hipStream_t stream) {
    const int*   x    = (const int*)d_in[0];
    const float* tv   = (const float*)d_in[1];
    const float* emb  = (const float*)d_in[2];
    const float* wih1 = (const float*)d_in[3];
    const float* whh1 = (const float*)d_in[4];
    const float* bih1 = (const float*)d_in[5];
    const float* bhh1 = (const float*)d_in[6];
    const float* g1   = (const float*)d_in[7];
    const float* be1  = (const float*)d_in[8];
    const float* wih2 = (const float*)d_in[9];
    const float* whh2 = (const float*)d_in[10];
    const float* bih2 = (const float*)d_in[11];
    const float* bhh2 = (const float*)d_in[12];
    const float* g2   = (const float*)d_in[13];
    const float* be2  = (const float*)d_in[14];
    const float* fcw  = (const float*)d_in[15];
    const float* fcb  = (const float*)d_in[16];
    const float* m1   = (const float*)d_in[17];
    const float* m2   = (const float*)d_in[18];

    char* w = (char*)d_ws;
    // counters first (all 64B-line spaced), then h-buffers -> one memset prefix
    int*    l1g    = (int*)(w);                         // 512*64B = 32 KB
    int*    l2g    = (int*)(w + 32768);                 // 32 KB
    int*    l1s    = (int*)(w + 65536);                 // 512*8*64B = 256 KB
    int*    l2s    = (int*)(w + 327680);                // 256 KB
    int*    poolg  = (int*)(w + 589824);                // 64 B
    int*    pools  = (int*)(w + 589824 + 64);           // 8*64B
    __bf16* h1buf  = (__bf16*)(w + 593920);             // 256 KB (2 slots)
    __bf16* h2buf  = (__bf16*)(w + 593920 + 262144);    // 256 KB
    __bf16* o1buf  = (__bf16*)(w + 1118208);            // 512 KB (4 slots)
    float*  pooled = (float*)(w + 1630208);             // 256 KB
    __bf16* xseq   = (__bf16*)(w + 1892352);            // 64 MB optional
    float*  out    = (float*)d_out;

    size_t need_xseq = (size_t)1892352 + (size_t)TDIM * BDIM * HDIM * 2;
    int use_xseq = (ws_size >= need_xseq) ? 1 : 0;

    // zero counters + h1/h2 initial state
    hipMemsetAsync(d_ws, 0, 1118208, stream);

    if (use_xseq)
        gather_emb<<<dim3(TDIM * BDIM), dim3(256), 0, stream>>>(x, emb, xseq);

    void* args[] = {&x, &tv, &emb, &wih1, &whh1, &bih1, &bhh1, &g1, &be1,
                    &wih2, &whh2, &bih2, &bhh2, &g2, &be2, &fcw, &fcb, &m1, &m2,
                    &xseq, &use_xseq,
                    &l1g, &l2g, &l1s, &l2s, &poolg, &pools,
                    &h1buf, &h2buf, &o1buf, &pooled, &out};
    hipLaunchCooperativeKernel((void*)rnn_all, dim3(256), dim3(512), args, 0, stream);
}

// Round 5
// 4305.774 us; speedup vs baseline: 9.9888x; 1.5920x over previous
//
#include <hip/hip_runtime.h>

#define HDIM  1024
#define BDIM  64
#define TDIM  512
#define FRAGB 131072            // bytes per fragment-order activation matrix (64x1024 bf16)
#define FRAGE 65536             // elements per fragment matrix
#define WPAD  1032              // weight LDS row stride in bf16
#define SLOTS 4                 // o1 ring slots
#define NGRP  8                 // arrival sub-groups per layer (16 blocks each)

typedef __bf16 bf16x8 __attribute__((ext_vector_type(8)));
typedef float  f32x4  __attribute__((ext_vector_type(4)));
typedef int    i32x4  __attribute__((ext_vector_type(4)));

#define MFMA(a, b, c) __builtin_amdgcn_mfma_f32_16x16x32_bf16(a, b, c, 0, 0, 0)

// MALL-coherent 16B load (bypasses L1+L2)
#define GL(dst, p, off) \
    asm volatile("global_load_dwordx4 %0, %1, off offset:" off " sc0 sc1" \
                 : "=v"(dst) : "v"(p) : "memory")
// 16 chunks x 1KB, chunk i at +i*1024B (13-bit offset limit -> 4 sub-pointers)
#define GLF16(f, p) do { \
    const char* p0_ = (const char*)(p); \
    const char* p1_ = p0_ + 4096; const char* p2_ = p0_ + 8192; const char* p3_ = p0_ + 12288; \
    GL(f[0],  p0_, "0"); GL(f[1],  p0_, "1024"); GL(f[2],  p0_, "2048"); GL(f[3],  p0_, "3072"); \
    GL(f[4],  p1_, "0"); GL(f[5],  p1_, "1024"); GL(f[6],  p1_, "2048"); GL(f[7],  p1_, "3072"); \
    GL(f[8],  p2_, "0"); GL(f[9],  p2_, "1024"); GL(f[10], p2_, "2048"); GL(f[11], p2_, "3072"); \
    GL(f[12], p3_, "0"); GL(f[13], p3_, "1024"); GL(f[14], p3_, "2048"); GL(f[15], p3_, "3072"); \
} while (0)
#define WAITV() asm volatile("s_waitcnt vmcnt(0)" ::: "memory")
#define GS16(p, v) \
    asm volatile("global_store_dwordx4 %0, %1, off sc0 sc1" :: "v"(p), "v"(v) : "memory")

__device__ __forceinline__ float sigf(float x) { return 1.0f / (1.0f + expf(-x)); }

__device__ __forceinline__ bf16x8 cvt8(const float* p) {
    const f32x4* q = (const f32x4*)p;
    f32x4 a = q[0], b = q[1];
    bf16x8 r;
    r[0] = (__bf16)a[0]; r[1] = (__bf16)a[1]; r[2] = (__bf16)a[2]; r[3] = (__bf16)a[3];
    r[4] = (__bf16)b[0]; r[5] = (__bf16)b[1]; r[6] = (__bf16)b[2]; r[7] = (__bf16)b[3];
    return r;
}

// ---- sync: 8 sub-counters (16-way fan-in each); consumers poll all 8 in parallel
__device__ __forceinline__ void spin2x8(const int* a, const int* b) {
    if (threadIdx.x < 64) {
        int l = threadIdx.x;
        const int* p = nullptr;
        if (l < 8)       { if (a) p = a + l * 16; }
        else if (l < 16) { if (b) p = b + (l - 8) * 16; }
        for (;;) {
            int v = 16;
            if (p) v = __hip_atomic_load(p, __ATOMIC_RELAXED, __HIP_MEMORY_SCOPE_AGENT);
            if (__all(v >= 16)) break;
            __builtin_amdgcn_s_sleep(1);
        }
    }
    __syncthreads();
}
__device__ __forceinline__ void arrive16(int* sub) {
    WAITV();                 // my wave's sc0sc1 stores reached MALL
    __syncthreads();         // whole block's stores done
    if (threadIdx.x == 0)
        __hip_atomic_fetch_add(sub, 1, __ATOMIC_RELAXED, __HIP_MEMORY_SCOPE_AGENT);
}
__device__ __forceinline__ void spin1(const int* c, int n) {
    if (threadIdx.x == 0)
        while (__hip_atomic_load(c, __ATOMIC_RELAXED, __HIP_MEMORY_SCOPE_AGENT) < n)
            __builtin_amdgcn_s_sleep(1);
    __syncthreads();
}

// Pre-pass: xseqfrag[t] = emb[x[:,t]] in MFMA A-fragment order
__global__ void gather_emb(const int* __restrict__ x, const float* __restrict__ emb,
                           __bf16* __restrict__ xseqfrag) {
    int t = blockIdx.x;
    for (int u = threadIdx.x; u < 8192; u += 256) {
        int lane = u & 63, c = (u >> 6) & 31, bt = u >> 11;
        int row = lane & 15, quad = lane >> 4;
        int b = bt * 16 + row, k = c * 32 + quad * 8;
        int tok = x[b * TDIM + t];
        bf16x8 r = cvt8(emb + (size_t)tok * HDIM + k);
        *(bf16x8*)(xseqfrag + (size_t)t * FRAGE + (size_t)u * 8) = r;
    }
}

__global__ void __launch_bounds__(512, 1) rnn_all(
    const int* __restrict__ x, const float* __restrict__ tv,
    const float* __restrict__ emb,
    const float* __restrict__ w_ih1, const float* __restrict__ w_hh1,
    const float* __restrict__ b_ih1, const float* __restrict__ b_hh1,
    const float* __restrict__ gamma1, const float* __restrict__ beta1,
    const float* __restrict__ w_ih2, const float* __restrict__ w_hh2,
    const float* __restrict__ b_ih2, const float* __restrict__ b_hh2,
    const float* __restrict__ gamma2, const float* __restrict__ beta2,
    const float* __restrict__ fc_w, const float* __restrict__ fc_b,
    const float* __restrict__ mask1, const float* __restrict__ mask2,
    const __bf16* __restrict__ xseq, int use_xseq,
    int* __restrict__ l1s, int* __restrict__ l2s, int* __restrict__ poolg,
    char* __restrict__ h1frag, char* __restrict__ h2frag,
    char* __restrict__ o1frag, float* __restrict__ pooled,
    float* __restrict__ out) {
    __shared__ __bf16 wih_s[32 * WPAD];
    __shared__ __bf16 whh_s[32 * WPAD];
    __shared__ float bias_s[32];
    __shared__ float gbuf[64 * 36];
    __shared__ float xh[8 * 68];
    __shared__ float stat_m[8], stat_r[8];
    __shared__ __align__(16) __bf16 hstage[512];
    __shared__ __align__(16) __bf16 ostage[512];

    const int tid   = threadIdx.x;
    const int layer = blockIdx.x & 1;
    const int lb    = blockIdx.x >> 1;      // 0..127 within layer group
    const int grp   = lb >> 4;              // 0..7 arrival sub-group
    const int fbase = lb * 8;

    const float* w_ih = layer ? w_ih2 : w_ih1;
    const float* w_hh = layer ? w_hh2 : w_hh1;
    const float* b_ih = layer ? b_ih2 : b_ih1;
    const float* b_hh = layer ? b_hh2 : b_hh1;
    const float* gam_ = layer ? gamma2 : gamma1;
    const float* bet_ = layer ? beta2  : beta1;
    const float* msk_ = layer ? mask2  : mask1;

    for (int idx = tid; idx < 32 * HDIM; idx += 512) {
        int n = idx >> 10, k = idx & 1023;
        int row = (n >> 3) * HDIM + fbase + (n & 7);
        wih_s[n * WPAD + k] = (__bf16)w_ih[row * HDIM + k];
        whh_s[n * WPAD + k] = (__bf16)w_hh[row * HDIM + k];
    }
    if (tid < 32) {
        int row = (tid >> 3) * HDIM + fbase + (tid & 7);
        bias_s[tid] = b_ih[row] + b_hh[row];
    }
    __syncthreads();

    // GEMM roles: wave = (batch-tile, K-half); each block reads each A-byte once
    const int lane = tid & 63;
    const int wv   = tid >> 6;          // 0..7
    const int bt   = wv & 3;            // batch tile
    const int kh   = wv >> 2;           // K half
    const int qm   = lane & 15;
    const int quad = lane >> 4;
    const int kbase = kh * 512 + quad * 8;
    const int fragoff = ((bt * 32 + kh * 16) * 64 + lane) * 16;   // byte offset of chunk 0

    const __bf16* bwi0 = wih_s + qm * WPAD + kbase;
    const __bf16* bwi1 = wih_s + (16 + qm) * WPAD + kbase;
    const __bf16* bwh0 = whh_s + qm * WPAD + kbase;
    const __bf16* bwh1 = whh_s + (16 + qm) * WPAD + kbase;

    // cell roles + producer store-phase address (fragment layout)
    const int bb = tid >> 3, jj = tid & 7;
    const int feat = fbase + jj;
    const float gv = gam_[feat], bev = bet_[feat], mv = msk_[bb * HDIM + feat];
    float c = 0.0f, pmax = -1e30f;

    const int sbb  = tid & 63;          // store-phase batch row
    const int soff = (((sbb >> 4) * 32 + (lb >> 2)) * 64 + ((lb & 3) * 16 + (sbb & 15))) * 16;

#pragma unroll 1
    for (int t = 0; t < TDIM; t++) {
        f32x4 ax0 = {0.f,0.f,0.f,0.f}, ax1 = {0.f,0.f,0.f,0.f};
        f32x4 ah0 = {0.f,0.f,0.f,0.f}, ah1 = {0.f,0.f,0.f,0.f};
        bf16x8 fh[16];

        if (layer == 0) {
            // ---- x-GEMM off the critical path (cached, coalesced frag loads) ----
            if (use_xseq) {
                const __bf16* a = xseq + (size_t)t * FRAGE + (fragoff >> 1);
#pragma unroll 4
                for (int i = 0; i < 16; i++) {
                    bf16x8 va = *(const bf16x8*)(a + i * 512);
                    ax0 = MFMA(va, *(const bf16x8*)(bwi0 + i * 32), ax0);
                    ax1 = MFMA(va, *(const bf16x8*)(bwi1 + i * 32), ax1);
                }
            } else {
                const float* a = emb + (size_t)x[(bt * 16 + qm) * TDIM + t] * HDIM + kbase;
#pragma unroll 4
                for (int i = 0; i < 16; i++) {
                    bf16x8 va = cvt8(a + i * 32);
                    ax0 = MFMA(va, *(const bf16x8*)(bwi0 + i * 32), ax0);
                    ax1 = MFMA(va, *(const bf16x8*)(bwi1 + i * 32), ax1);
                }
            }
            spin2x8(t >= 1 ? l1s + (size_t)(t - 1) * NGRP * 16 : nullptr,
                    t >= SLOTS ? l2s + (size_t)(t - SLOTS) * NGRP * 16 : nullptr);
            GLF16(fh, h1frag + (size_t)(t & 1) * FRAGB + fragoff);
            WAITV();
#pragma unroll
            for (int i = 0; i < 16; i++) {
                ah0 = MFMA(fh[i], *(const bf16x8*)(bwh0 + i * 32), ah0);
                ah1 = MFMA(fh[i], *(const bf16x8*)(bwh1 + i * 32), ah1);
            }
        } else {
            spin2x8(l1s + (size_t)t * NGRP * 16,
                    t >= 1 ? l2s + (size_t)(t - 1) * NGRP * 16 : nullptr);
            bf16x8 fo[16];
            GLF16(fo, o1frag + (size_t)(t & (SLOTS - 1)) * FRAGB + fragoff);
            GLF16(fh, h2frag + (size_t)(t & 1) * FRAGB + fragoff);
            WAITV();
#pragma unroll
            for (int i = 0; i < 16; i++) {
                ax0 = MFMA(fo[i], *(const bf16x8*)(bwi0 + i * 32), ax0);
                ax1 = MFMA(fo[i], *(const bf16x8*)(bwi1 + i * 32), ax1);
                ah0 = MFMA(fh[i], *(const bf16x8*)(bwh0 + i * 32), ah0);
                ah1 = MFMA(fh[i], *(const bf16x8*)(bwh1 + i * 32), ah1);
            }
        }

        // ---- combine K-halves in LDS, add bias ----
        if (kh == 0) {
#pragma unroll
            for (int r = 0; r < 4; r++) {
                int row = (bt * 16 + quad * 4 + r) * 36;
                gbuf[row + qm]      = ax0[r] + ah0[r] + bias_s[qm];
                gbuf[row + 16 + qm] = ax1[r] + ah1[r] + bias_s[16 + qm];
            }
        }
        __syncthreads();
        if (kh == 1) {
#pragma unroll
            for (int r = 0; r < 4; r++) {
                int row = (bt * 16 + quad * 4 + r) * 36;
                gbuf[row + qm]      += ax0[r] + ah0[r];
                gbuf[row + 16 + qm] += ax1[r] + ah1[r];
            }
        }
        __syncthreads();

        // ---- LSTM cell + BN + mask ----
        float gi = gbuf[bb * 36 + jj];
        float gf = gbuf[bb * 36 + 8 + jj];
        float gg = gbuf[bb * 36 + 16 + jj];
        float go = gbuf[bb * 36 + 24 + jj];
        c = sigf(gf) * c + sigf(gi) * tanhf(gg);
        float h = sigf(go) * tanhf(c);
        hstage[tid] = (__bf16)h;
        xh[jj * 68 + bb] = h;
        __syncthreads();
        float v = xh[wv * 68 + lane];
        float s1 = v, s2 = v * v;
#pragma unroll
        for (int off = 32; off; off >>= 1) {
            s1 += __shfl_xor(s1, off);
            s2 += __shfl_xor(s2, off);
        }
        if (lane == 0) {
            float m  = s1 * (1.0f / 64.0f);
            float va = s2 * (1.0f / 64.0f) - m * m;
            stat_m[wv] = m;
            stat_r[wv] = rsqrtf(va + 1e-5f);
        }
        __syncthreads();
        float o = ((h - stat_m[jj]) * stat_r[jj] * gv + bev) * mv;
        if (layer == 0) ostage[tid] = (__bf16)o;
        else            pmax = fmaxf(pmax, o);
        __syncthreads();

        // ---- packed 16B fragment-order stores (64 units per matrix) ----
        if (layer == 0) {
            if (tid < 64) {
                i32x4 val = *(const i32x4*)(hstage + tid * 8);
                GS16(h1frag + (size_t)((t + 1) & 1) * FRAGB + soff, val);
            } else if (tid < 128) {
                i32x4 val = *(const i32x4*)(ostage + (tid - 64) * 8);
                GS16(o1frag + (size_t)(t & (SLOTS - 1)) * FRAGB + soff, val);
            }
            arrive16(l1s + ((size_t)t * NGRP + grp) * 16);
        } else {
            if (tid < 64) {
                i32x4 val = *(const i32x4*)(hstage + tid * 8);
                GS16(h2frag + (size_t)((t + 1) & 1) * FRAGB + soff, val);
            }
            arrive16(l2s + ((size_t)t * NGRP + grp) * 16);
        }
    }

    if (layer == 1) {
        __hip_atomic_store(&pooled[bb * HDIM + feat], pmax,
                           __ATOMIC_RELAXED, __HIP_MEMORY_SCOPE_AGENT);
        WAITV();
        __syncthreads();
        if (tid == 0)
            __hip_atomic_fetch_add(poolg, 1, __ATOMIC_RELAXED, __HIP_MEMORY_SCOPE_AGENT);

        if (lb == 0) {
            // ============== FC + BCE loss (one block) ==============
            spin1(poolg, 128);
            __builtin_amdgcn_fence(__ATOMIC_ACQUIRE, "agent");
            int b  = wv * 8 + (lane >> 3);
            int l8 = lane & 7;
            float s = 0.0f;
            for (int f = l8 * 128; f < l8 * 128 + 128; f++)
                s += pooled[b * HDIM + f] * fc_w[f];
            s += __shfl_xor(s, 1); s += __shfl_xor(s, 2); s += __shfl_xor(s, 4);
            float logit = s + fc_b[0];
            if (l8 == 0) {
                out[1 + b] = logit;
                gbuf[b] = fmaxf(logit, 0.0f) - logit * tv[b] + log1pf(expf(-fabsf(logit)));
            }
            __syncthreads();
            if (tid < 64) {
                float term = gbuf[tid];
#pragma unroll
                for (int off = 32; off; off >>= 1) term += __shfl_xor(term, off);
                if (tid == 0) out[0] = term * (1.0f / 64.0f);
            }
        }
    }
}

extern "C" void kernel_launch(void* const* d_in, const int* in_sizes, int n_in,
                              void* d_out, int out_size, void* d_ws, size_t ws_size,
                              hipStream_t stream) {
    const int*   x    = (const int*)d_in[0];
    const float* tv   = (const float*)d_in[1];
    const float* emb  = (const float*)d_in[2];
    const float* wih1 = (const float*)d_in[3];
    const float* whh1 = (const float*)d_in[4];
    const float* bih1 = (const float*)d_in[5];
    const float* bhh1 = (const float*)d_in[6];
    const float* g1   = (const float*)d_in[7];
    const float* be1  = (const float*)d_in[8];
    const float* wih2 = (const float*)d_in[9];
    const float* whh2 = (const float*)d_in[10];
    const float* bih2 = (const float*)d_in[11];
    const float* bhh2 = (const float*)d_in[12];
    const float* g2   = (const float*)d_in[13];
    const float* be2  = (const float*)d_in[14];
    const float* fcw  = (const float*)d_in[15];
    const float* fcb  = (const float*)d_in[16];
    const float* m1   = (const float*)d_in[17];
    const float* m2   = (const float*)d_in[18];

    char* w = (char*)d_ws;
    int*    l1s    = (int*)(w);                    // 512*8*64B = 256 KB
    int*    l2s    = (int*)(w + 262144);           // 256 KB
    int*    poolg  = (int*)(w + 524288);           // 64 B (pad 4 KB)
    char*   h1frag = w + 528384;                   // 256 KB (2 slots)
    char*   h2frag = w + 528384 + 262144;          // 256 KB
    char*   o1frag = w + 1052672;                  // 512 KB (4 slots)
    float*  pooled = (float*)(w + 1576960);        // 256 KB
    __bf16* xseq   = (__bf16*)(w + 1839104);       // 64 MB optional
    float*  out    = (float*)d_out;

    size_t need_xseq = (size_t)1839104 + (size_t)TDIM * FRAGB;
    int use_xseq = (ws_size >= need_xseq) ? 1 : 0;

    // zero counters + h1/h2 initial state
    hipMemsetAsync(d_ws, 0, 1052672, stream);

    if (use_xseq)
        gather_emb<<<dim3(TDIM), dim3(256), 0, stream>>>(x, emb, xseq);

    void* args[] = {&x, &tv, &emb, &wih1, &whh1, &bih1, &bhh1, &g1, &be1,
                    &wih2, &whh2, &bih2, &bhh2, &g2, &be2, &fcw, &fcb, &m1, &m2,
                    &xseq, &use_xseq,
                    &l1s, &l2s, &poolg,
                    &h1frag, &h2frag, &o1frag, &pooled, &out};
    hipLaunchCooperativeKernel((void*)rnn_all, dim3(256), dim3(512), args, 0, stream);
}

// Round 6
// 4069.930 us; speedup vs baseline: 10.5676x; 1.0579x over previous
//
#include <hip/hip_runtime.h>

#define HDIM  1024
#define BDIM  64
#define TDIM  512
#define FRAGB 131072            // bytes per fragment-order activation matrix (64x1024 bf16)
#define FRAGE 65536             // elements per fragment matrix
#define WPAD  1048              // weight LDS row stride in bf16 (524 words, %32=12 -> spread)
#define SLOTS 4                 // o1 ring slots (small mode only)
#define NGRP  8                 // arrival sub-groups per layer (16 blocks each)

typedef __bf16 bf16x8 __attribute__((ext_vector_type(8)));
typedef float  f32x4  __attribute__((ext_vector_type(4)));
typedef int    i32x4  __attribute__((ext_vector_type(4)));

#define MFMA(a, b, c) __builtin_amdgcn_mfma_f32_16x16x32_bf16(a, b, c, 0, 0, 0)

// MALL-coherent 16B load (bypasses L1+L2) -- small mode only
#define GL(dst, p, off) \
    asm volatile("global_load_dwordx4 %0, %1, off offset:" off " sc0 sc1" \
                 : "=v"(dst) : "v"(p) : "memory")
#define GLF16(f, p) do { \
    const char* p0_ = (const char*)(p); \
    const char* p1_ = p0_ + 4096; const char* p2_ = p0_ + 8192; const char* p3_ = p0_ + 12288; \
    GL(f[0],  p0_, "0"); GL(f[1],  p0_, "1024"); GL(f[2],  p0_, "2048"); GL(f[3],  p0_, "3072"); \
    GL(f[4],  p1_, "0"); GL(f[5],  p1_, "1024"); GL(f[6],  p1_, "2048"); GL(f[7],  p1_, "3072"); \
    GL(f[8],  p2_, "0"); GL(f[9],  p2_, "1024"); GL(f[10], p2_, "2048"); GL(f[11], p2_, "3072"); \
    GL(f[12], p3_, "0"); GL(f[13], p3_, "1024"); GL(f[14], p3_, "2048"); GL(f[15], p3_, "3072"); \
} while (0)
#define WAITV() asm volatile("s_waitcnt vmcnt(0)" ::: "memory")
#define GS16(p, v) \
    asm volatile("global_store_dwordx4 %0, %1, off sc0 sc1" :: "v"(p), "v"(v) : "memory")

__device__ __forceinline__ float sigf(float x) { return 1.0f / (1.0f + expf(-x)); }

__device__ __forceinline__ bf16x8 cvt8(const float* p) {
    const f32x4* q = (const f32x4*)p;
    f32x4 a = q[0], b = q[1];
    bf16x8 r;
    r[0] = (__bf16)a[0]; r[1] = (__bf16)a[1]; r[2] = (__bf16)a[2]; r[3] = (__bf16)a[3];
    r[4] = (__bf16)b[0]; r[5] = (__bf16)b[1]; r[6] = (__bf16)b[2]; r[7] = (__bf16)b[3];
    return r;
}

// cached fragment load: 16 x 1KB coalesced, L1/L2 cached (t-indexed => never stale)
__device__ __forceinline__ void load16c(bf16x8* f, const char* p) {
#pragma unroll
    for (int i = 0; i < 16; i++) f[i] = *(const bf16x8*)(p + i * 1024);
}

// ---- sync: 8 sub-counters (16-way fan-in); consumers poll all in parallel ----
__device__ __forceinline__ void spin2x8(const int* a, const int* b) {
    if (threadIdx.x < 64) {
        int l = threadIdx.x;
        const int* p = nullptr;
        if (l < 8)       { if (a) p = a + l * 16; }
        else if (l < 16) { if (b) p = b + (l - 8) * 16; }
        for (;;) {
            int v = 16;
            if (p) v = __hip_atomic_load(p, __ATOMIC_RELAXED, __HIP_MEMORY_SCOPE_AGENT);
            if (__all(v >= 16)) break;
            __builtin_amdgcn_s_sleep(1);
        }
    }
    __syncthreads();
}
__device__ __forceinline__ void arrive16(int* sub) {
    WAITV();                 // my wave's sc0sc1 stores reached MALL
    __syncthreads();         // whole block's stores done
    if (threadIdx.x == 0)
        __hip_atomic_fetch_add(sub, 1, __ATOMIC_RELAXED, __HIP_MEMORY_SCOPE_AGENT);
}
__device__ __forceinline__ void spin1(const int* c, int n) {
    if (threadIdx.x == 0)
        while (__hip_atomic_load(c, __ATOMIC_RELAXED, __HIP_MEMORY_SCOPE_AGENT) < n)
            __builtin_amdgcn_s_sleep(1);
    __syncthreads();
}

// Pre-pass: xseqfrag[t] = emb[x[:,t]] in MFMA A-fragment order
__global__ void gather_emb(const int* __restrict__ x, const float* __restrict__ emb,
                           __bf16* __restrict__ xseqfrag) {
    int t = blockIdx.x;
    for (int u = threadIdx.x; u < 8192; u += 256) {
        int lane = u & 63, c = (u >> 6) & 31, bt = u >> 11;
        int row = lane & 15, quad = lane >> 4;
        int b = bt * 16 + row, k = c * 32 + quad * 8;
        int tok = x[b * TDIM + t];
        bf16x8 r = cvt8(emb + (size_t)tok * HDIM + k);
        *(bf16x8*)(xseqfrag + (size_t)t * FRAGE + (size_t)u * 8) = r;
    }
}

template <int BIG>
__global__ void __launch_bounds__(512, 1) rnn_all(
    const int* __restrict__ x, const float* __restrict__ tv,
    const float* __restrict__ emb,
    const float* __restrict__ w_ih1, const float* __restrict__ w_hh1,
    const float* __restrict__ b_ih1, const float* __restrict__ b_hh1,
    const float* __restrict__ gamma1, const float* __restrict__ beta1,
    const float* __restrict__ w_ih2, const float* __restrict__ w_hh2,
    const float* __restrict__ b_ih2, const float* __restrict__ b_hh2,
    const float* __restrict__ gamma2, const float* __restrict__ beta2,
    const float* __restrict__ fc_w, const float* __restrict__ fc_b,
    const float* __restrict__ mask1, const float* __restrict__ mask2,
    const __bf16* __restrict__ xseq, int use_xseq,
    int* __restrict__ l1s, int* __restrict__ l2s, int* __restrict__ poolg,
    const char* __restrict__ hzero,
    char* __restrict__ h1p, char* __restrict__ h2p, char* __restrict__ o1p,
    float* __restrict__ pooled, float* __restrict__ out) {
    __shared__ __bf16 wih_s[32 * WPAD];
    __shared__ __bf16 whh_s[32 * WPAD];
    __shared__ float bias_s[32];
    __shared__ float gbuf[64 * 36];
    __shared__ float xh[8 * 68];
    __shared__ float stat_m[8], stat_r[8];
    __shared__ __align__(16) __bf16 hstage[512];
    __shared__ __align__(16) __bf16 ostage[512];

    const int tid   = threadIdx.x;
    const int layer = blockIdx.x & 1;
    const int lb    = blockIdx.x >> 1;      // 0..127 within layer group
    const int grp   = lb >> 4;              // 0..7 arrival sub-group
    const int fbase = lb * 8;

    const float* w_ih = layer ? w_ih2 : w_ih1;
    const float* w_hh = layer ? w_hh2 : w_hh1;
    const float* b_ih = layer ? b_ih2 : b_ih1;
    const float* b_hh = layer ? b_hh2 : b_hh1;
    const float* gam_ = layer ? gamma2 : gamma1;
    const float* bet_ = layer ? beta2  : beta1;
    const float* msk_ = layer ? mask2  : mask1;

    for (int idx = tid; idx < 32 * HDIM; idx += 512) {
        int n = idx >> 10, k = idx & 1023;
        int row = (n >> 3) * HDIM + fbase + (n & 7);
        wih_s[n * WPAD + k] = (__bf16)w_ih[row * HDIM + k];
        whh_s[n * WPAD + k] = (__bf16)w_hh[row * HDIM + k];
    }
    if (tid < 32) {
        int row = (tid >> 3) * HDIM + fbase + (tid & 7);
        bias_s[tid] = b_ih[row] + b_hh[row];
    }
    __syncthreads();
    if (BIG) // drop any pre-kernel (poison/memset) lines from this XCD's caches
        __builtin_amdgcn_fence(__ATOMIC_ACQUIRE, "agent");

    // GEMM roles: wave = (batch-tile, K-half); each block reads each A-byte once
    const int lane = tid & 63;
    const int wv   = tid >> 6;          // 0..7
    const int bt   = wv & 3;            // batch tile
    const int kh   = wv >> 2;           // K half
    const int qm   = lane & 15;
    const int quad = lane >> 4;
    const int kbase = kh * 512 + quad * 8;
    const int fragoff = ((bt * 32 + kh * 16) * 64 + lane) * 16;   // byte offset of chunk 0

    const __bf16* bwi0 = wih_s + qm * WPAD + kbase;
    const __bf16* bwi1 = wih_s + (16 + qm) * WPAD + kbase;
    const __bf16* bwh0 = whh_s + qm * WPAD + kbase;
    const __bf16* bwh1 = whh_s + (16 + qm) * WPAD + kbase;

    const int bb = tid >> 3, jj = tid & 7;
    const int feat = fbase + jj;
    const float gv = gam_[feat], bev = bet_[feat], mv = msk_[bb * HDIM + feat];
    float c = 0.0f, pmax = -1e30f;

    const int sbb  = tid & 63;          // store-phase batch row
    const int soff = (((sbb >> 4) * 32 + (lb >> 2)) * 64 + ((lb & 3) * 16 + (sbb & 15))) * 16;

#pragma unroll 1
    for (int t = 0; t < TDIM; t++) {
        f32x4 ax0 = {0.f,0.f,0.f,0.f}, ax1 = {0.f,0.f,0.f,0.f};
        f32x4 ah0 = {0.f,0.f,0.f,0.f}, ah1 = {0.f,0.f,0.f,0.f};
        bf16x8 fh[16];

        if (layer == 0) {
            // ---- x-GEMM off the critical path (cached frag loads) ----
            if (use_xseq) {
                const __bf16* a = xseq + (size_t)t * FRAGE + (fragoff >> 1);
#pragma unroll 4
                for (int i = 0; i < 16; i++) {
                    bf16x8 va = *(const bf16x8*)(a + i * 512);
                    ax0 = MFMA(va, *(const bf16x8*)(bwi0 + i * 32), ax0);
                    ax1 = MFMA(va, *(const bf16x8*)(bwi1 + i * 32), ax1);
                }
            } else {
                const float* a = emb + (size_t)x[(bt * 16 + qm) * TDIM + t] * HDIM + kbase;
#pragma unroll 4
                for (int i = 0; i < 16; i++) {
                    bf16x8 va = cvt8(a + i * 32);
                    ax0 = MFMA(va, *(const bf16x8*)(bwi0 + i * 32), ax0);
                    ax1 = MFMA(va, *(const bf16x8*)(bwi1 + i * 32), ax1);
                }
            }
            if (BIG) {
                spin2x8(t >= 1 ? l1s + (size_t)(t - 1) * NGRP * 16 : nullptr, nullptr);
                const char* src = (t == 0) ? hzero : h1p + (size_t)(t - 1) * FRAGB;
                load16c(fh, src + fragoff);
            } else {
                spin2x8(t >= 1 ? l1s + (size_t)(t - 1) * NGRP * 16 : nullptr,
                        t >= SLOTS ? l2s + (size_t)(t - SLOTS) * NGRP * 16 : nullptr);
                GLF16(fh, h1p + (size_t)(t & 1) * FRAGB + fragoff);
                WAITV();
            }
#pragma unroll
            for (int i = 0; i < 16; i++) {
                ah0 = MFMA(fh[i], *(const bf16x8*)(bwh0 + i * 32), ah0);
                ah1 = MFMA(fh[i], *(const bf16x8*)(bwh1 + i * 32), ah1);
            }
        } else {
            bf16x8 fo[16];
            if (BIG) {
                spin2x8(l1s + (size_t)t * NGRP * 16,
                        t >= 1 ? l2s + (size_t)(t - 1) * NGRP * 16 : nullptr);
                load16c(fo, o1p + (size_t)t * FRAGB + fragoff);
                const char* src = (t == 0) ? hzero : h2p + (size_t)(t - 1) * FRAGB;
                load16c(fh, src + fragoff);
            } else {
                spin2x8(l1s + (size_t)t * NGRP * 16,
                        t >= 1 ? l2s + (size_t)(t - 1) * NGRP * 16 : nullptr);
                GLF16(fo, o1p + (size_t)(t & (SLOTS - 1)) * FRAGB + fragoff);
                GLF16(fh, h2p + (size_t)(t & 1) * FRAGB + fragoff);
                WAITV();
            }
#pragma unroll
            for (int i = 0; i < 16; i++) {
                ax0 = MFMA(fo[i], *(const bf16x8*)(bwi0 + i * 32), ax0);
                ax1 = MFMA(fo[i], *(const bf16x8*)(bwi1 + i * 32), ax1);
                ah0 = MFMA(fh[i], *(const bf16x8*)(bwh0 + i * 32), ah0);
                ah1 = MFMA(fh[i], *(const bf16x8*)(bwh1 + i * 32), ah1);
            }
        }

        // ---- combine K-halves in LDS, add bias ----
        if (kh == 0) {
#pragma unroll
            for (int r = 0; r < 4; r++) {
                int row = (bt * 16 + quad * 4 + r) * 36;
                gbuf[row + qm]      = ax0[r] + ah0[r] + bias_s[qm];
                gbuf[row + 16 + qm] = ax1[r] + ah1[r] + bias_s[16 + qm];
            }
        }
        __syncthreads();
        if (kh == 1) {
#pragma unroll
            for (int r = 0; r < 4; r++) {
                int row = (bt * 16 + quad * 4 + r) * 36;
                gbuf[row + qm]      += ax0[r] + ah0[r];
                gbuf[row + 16 + qm] += ax1[r] + ah1[r];
            }
        }
        __syncthreads();

        // ---- LSTM cell + BN + mask ----
        float gi = gbuf[bb * 36 + jj];
        float gf = gbuf[bb * 36 + 8 + jj];
        float gg = gbuf[bb * 36 + 16 + jj];
        float go = gbuf[bb * 36 + 24 + jj];
        c = sigf(gf) * c + sigf(gi) * tanhf(gg);
        float h = sigf(go) * tanhf(c);
        hstage[tid] = (__bf16)h;
        xh[jj * 68 + bb] = h;
        __syncthreads();
        float v = xh[wv * 68 + lane];
        float s1 = v, s2 = v * v;
#pragma unroll
        for (int off = 32; off; off >>= 1) {
            s1 += __shfl_xor(s1, off);
            s2 += __shfl_xor(s2, off);
        }
        if (lane == 0) {
            float m  = s1 * (1.0f / 64.0f);
            float va = s2 * (1.0f / 64.0f) - m * m;
            stat_m[wv] = m;
            stat_r[wv] = rsqrtf(va + 1e-5f);
        }
        __syncthreads();
        float o = ((h - stat_m[jj]) * stat_r[jj] * gv + bev) * mv;
        if (layer == 0) ostage[tid] = (__bf16)o;
        else            pmax = fmaxf(pmax, o);
        __syncthreads();

        // ---- packed 16B fragment-order stores (write-through to MALL) ----
        if (layer == 0) {
            size_t hslot = BIG ? (size_t)t * FRAGB : (size_t)((t + 1) & 1) * FRAGB;
            size_t oslot = BIG ? (size_t)t * FRAGB : (size_t)(t & (SLOTS - 1)) * FRAGB;
            if (tid < 64) {
                i32x4 val = *(const i32x4*)(hstage + tid * 8);
                GS16(h1p + hslot + soff, val);
            } else if (tid < 128) {
                i32x4 val = *(const i32x4*)(ostage + (tid - 64) * 8);
                GS16(o1p + oslot + soff, val);
            }
            arrive16(l1s + ((size_t)t * NGRP + grp) * 16);
        } else {
            size_t hslot = BIG ? (size_t)t * FRAGB : (size_t)((t + 1) & 1) * FRAGB;
            if (tid < 64) {
                i32x4 val = *(const i32x4*)(hstage + tid * 8);
                GS16(h2p + hslot + soff, val);
            }
            arrive16(l2s + ((size_t)t * NGRP + grp) * 16);
        }
    }

    if (layer == 1) {
        __hip_atomic_store(&pooled[bb * HDIM + feat], pmax,
                           __ATOMIC_RELAXED, __HIP_MEMORY_SCOPE_AGENT);
        WAITV();
        __syncthreads();
        if (tid == 0)
            __hip_atomic_fetch_add(poolg, 1, __ATOMIC_RELAXED, __HIP_MEMORY_SCOPE_AGENT);

        if (lb == 0) {
            // ============== FC + BCE loss (one block) ==============
            spin1(poolg, 128);
            __builtin_amdgcn_fence(__ATOMIC_ACQUIRE, "agent");
            int b  = wv * 8 + (lane >> 3);
            int l8 = lane & 7;
            float s = 0.0f;
            for (int f = l8 * 128; f < l8 * 128 + 128; f++)
                s += pooled[b * HDIM + f] * fc_w[f];
            s += __shfl_xor(s, 1); s += __shfl_xor(s, 2); s += __shfl_xor(s, 4);
            float logit = s + fc_b[0];
            if (l8 == 0) {
                out[1 + b] = logit;
                gbuf[b] = fmaxf(logit, 0.0f) - logit * tv[b] + log1pf(expf(-fabsf(logit)));
            }
            __syncthreads();
            if (tid < 64) {
                float term = gbuf[tid];
#pragma unroll
                for (int off = 32; off; off >>= 1) term += __shfl_xor(term, off);
                if (tid == 0) out[0] = term * (1.0f / 64.0f);
            }
        }
    }
}

extern "C" void kernel_launch(void* const* d_in, const int* in_sizes, int n_in,
                              void* d_out, int out_size, void* d_ws, size_t ws_size,
                              hipStream_t stream) {
    const int*   x    = (const int*)d_in[0];
    const float* tv   = (const float*)d_in[1];
    const float* emb  = (const float*)d_in[2];
    const float* wih1 = (const float*)d_in[3];
    const float* whh1 = (const float*)d_in[4];
    const float* bih1 = (const float*)d_in[5];
    const float* bhh1 = (const float*)d_in[6];
    const float* g1   = (const float*)d_in[7];
    const float* be1  = (const float*)d_in[8];
    const float* wih2 = (const float*)d_in[9];
    const float* whh2 = (const float*)d_in[10];
    const float* bih2 = (const float*)d_in[11];
    const float* bhh2 = (const float*)d_in[12];
    const float* g2   = (const float*)d_in[13];
    const float* be2  = (const float*)d_in[14];
    const float* fcw  = (const float*)d_in[15];
    const float* fcb  = (const float*)d_in[16];
    const float* m1   = (const float*)d_in[17];
    const float* m2   = (const float*)d_in[18];

    char* w = (char*)d_ws;
    float* out = (float*)d_out;

    // ---- big (t-indexed, L2-cached broadcast) layout ----
    const size_t SEQB = (size_t)TDIM * FRAGB;                  // 64 MB
    size_t boff = 0;
    int*   B_l1s   = (int*)(w + boff); boff += 262144;
    int*   B_l2s   = (int*)(w + boff); boff += 262144;
    int*   B_poolg = (int*)(w + boff); boff += 4096;
    char*  B_hzero = w + boff;         boff += FRAGB;          // memset prefix ends here
    size_t B_msz   = boff;
    char*  B_h1    = w + boff;         boff += SEQB;
    char*  B_h2    = w + boff;         boff += SEQB;
    char*  B_o1    = w + boff;         boff += SEQB;
    float* B_pool  = (float*)(w + boff); boff += 262144;
    __bf16* B_xseq = (__bf16*)(w + boff); boff += SEQB;
    size_t need_big = boff;

    if (ws_size >= need_big) {
        hipMemsetAsync(d_ws, 0, B_msz, stream);
        gather_emb<<<dim3(TDIM), dim3(256), 0, stream>>>(x, emb, B_xseq);
        int use_xseq = 1;
        void* args[] = {&x, &tv, &emb, &wih1, &whh1, &bih1, &bhh1, &g1, &be1,
                        &wih2, &whh2, &bih2, &bhh2, &g2, &be2, &fcw, &fcb, &m1, &m2,
                        (void*)&B_xseq, &use_xseq,
                        &B_l1s, &B_l2s, &B_poolg, (void*)&B_hzero,
                        &B_h1, &B_h2, &B_o1, &B_pool, &out};
        hipLaunchCooperativeKernel((void*)rnn_all<1>, dim3(256), dim3(512), args, 0, stream);
        return;
    }

    // ---- small fallback (round-5 behavior: sc0sc1 ring buffers) ----
    int*    l1s    = (int*)(w);
    int*    l2s    = (int*)(w + 262144);
    int*    poolg  = (int*)(w + 524288);
    char*   hzero  = w + 524288 + 4096;            // unused in small mode
    char*   h1frag = w + 528384 + FRAGB;           // 256 KB (2 slots)
    char*   h2frag = h1frag + 262144;              // 256 KB
    char*   o1frag = h2frag + 262144;              // 512 KB (4 slots)
    float*  pooled = (float*)(o1frag + 524288);
    __bf16* xseq   = (__bf16*)((char*)pooled + 262144);
    size_t fixed   = (size_t)((char*)xseq - w);
    int use_xseq = (ws_size >= fixed + SEQB) ? 1 : 0;

    hipMemsetAsync(d_ws, 0, fixed, stream);
    if (use_xseq)
        gather_emb<<<dim3(TDIM), dim3(256), 0, stream>>>(x, emb, xseq);

    void* args[] = {&x, &tv, &emb, &wih1, &whh1, &bih1, &bhh1, &g1, &be1,
                    &wih2, &whh2, &bih2, &bhh2, &g2, &be2, &fcw, &fcb, &m1, &m2,
                    (void*)&xseq, &use_xseq,
                    &l1s, &l2s, &poolg, (void*)&hzero,
                    &h1frag, &h2frag, &o1frag, &pooled, &out};
    hipLaunchCooperativeKernel((void*)rnn_all<0>, dim3(256), dim3(512), args, 0, stream);
}